// Round 1
// baseline (1543.824 us; speedup 1.0000x reference)
//
#include <hip/hip_runtime.h>

typedef short bf16x8 __attribute__((ext_vector_type(8)));
typedef _Float16 f16x8 __attribute__((ext_vector_type(8)));
typedef float f32x4 __attribute__((ext_vector_type(4)));
typedef _Float16 f16;
typedef unsigned short u16;
typedef unsigned int u32;

#define DEVFN static __device__ __forceinline__

// ---------- helpers ----------
DEVFN u16 f2bf(float f) {
  u32 u = __builtin_bit_cast(u32, f);
  return (u16)((u + 0x7FFFu + ((u >> 16) & 1u)) >> 16);
}

DEVFN void glds16(const void* g, void* l) {
  __builtin_amdgcn_global_load_lds((const __attribute__((address_space(1))) void*)g,
                                   (__attribute__((address_space(3))) void*)l, 16, 0, 0);
}

DEVFN void wsplit(f16* oh, f16* ol, long o, float v) {
  f16 hh = (f16)v;
  oh[o] = hh;
  ol[o] = (f16)((v - (float)hh) * 2048.0f);
}

// idx_q fragment-friendly layout: [row/16][h][kc][g][ri][8]
DEVFN long idxq_off(int row, int h, int c) {
  return ((((long)(row >> 4) * 16 + h) * 4 + (c >> 5)) * 4 + ((c >> 3) & 3)) * 128
         + (long)(row & 15) * 8 + (c & 7);
}

// ---------- elementwise conversions ----------
__global__ __launch_bounds__(256) void k_cvt_bf16(const float* __restrict__ in, u16* __restrict__ out, long n) {
  long i = ((long)blockIdx.x * 256 + threadIdx.x) * 4;
  if (i < n) {
    float4 v = *(const float4*)(in + i);
    out[i] = f2bf(v.x); out[i + 1] = f2bf(v.y); out[i + 2] = f2bf(v.z); out[i + 3] = f2bf(v.w);
  }
}

__global__ __launch_bounds__(256) void k_split(const float* __restrict__ in, f16* __restrict__ oh, f16* __restrict__ ol, long n) {
  long i = ((long)blockIdx.x * 256 + threadIdx.x) * 4;
  if (i < n) {
    float4 v = *(const float4*)(in + i);
    float a[4] = {v.x, v.y, v.z, v.w};
    #pragma unroll
    for (int k = 0; k < 4; ++k) {
      f16 hh = (f16)a[k];
      oh[i + k] = hh;
      ol[i + k] = (f16)((a[k] - (float)hh) * 2048.0f);
    }
  }
}

// wkv_b -> full bf16 copy + transposed nope part [h][c][d]
__global__ __launch_bounds__(256) void k_cvt_wkvb(const float* __restrict__ wkvb, u16* __restrict__ full_b, u16* __restrict__ nope_t) {
  long i = (long)blockIdx.x * 256 + threadIdx.x;
  if (i >= 2097152) return;
  float v = wkvb[i];
  u16 bv = f2bf(v);
  full_b[i] = bv;
  long row = i >> 9;
  int c = (int)(i & 511);
  int h = (int)(row >> 8);
  int d = (int)(row & 255);
  if (d < 128) nope_t[(long)h * 65536 + (long)c * 128 + d] = bv;
}

// ---------- generic C = A * B^T, bf16 MFMA, 128x128 tile ----------
__global__ __launch_bounds__(256) void k_gemm_bt(
    const u16* __restrict__ A, const u16* __restrict__ B, void* __restrict__ Cout,
    int N, int K, long lda, long ldb, long ldc, long sA, long sB, long sC, int outBf16) {
  A += (long)blockIdx.z * sA;
  B += (long)blockIdx.z * sB;
  const long m0 = (long)blockIdx.y * 128;
  const long n0 = (long)blockIdx.x * 128;
  __shared__ __align__(16) u16 As[128 * 32];
  __shared__ __align__(16) u16 Bs[128 * 32];
  const int tid = threadIdx.x;
  const int lane = tid & 63, wid = tid >> 6;
  const int g = lane >> 4, l16 = lane & 15;
  const int srow = tid >> 2;
  const int scol = (tid & 3) * 8;
  const int wm = wid >> 1, wn = wid & 1;
  f32x4 acc[4][4];
  #pragma unroll
  for (int m = 0; m < 4; ++m)
    #pragma unroll
    for (int n = 0; n < 4; ++n) acc[m][n] = (f32x4){0.f, 0.f, 0.f, 0.f};
  for (int k0 = 0; k0 < K; k0 += 32) {
    long rb0 = n0 + srow; if (rb0 >= N) rb0 = 0;
    long rb1 = n0 + 64 + srow; if (rb1 >= N) rb1 = 0;
    glds16(A + (m0 + srow) * lda + k0 + scol, As + (size_t)wid * 512);
    glds16(A + (m0 + 64 + srow) * lda + k0 + scol, As + 2048 + (size_t)wid * 512);
    glds16(B + rb0 * ldb + k0 + scol, Bs + (size_t)wid * 512);
    glds16(B + rb1 * ldb + k0 + scol, Bs + 2048 + (size_t)wid * 512);
    __syncthreads();
    bf16x8 af[4], bfv[4];
    #pragma unroll
    for (int m = 0; m < 4; ++m) af[m] = *(const bf16x8*)(As + (wm * 64 + m * 16 + l16) * 32 + g * 8);
    #pragma unroll
    for (int n = 0; n < 4; ++n) bfv[n] = *(const bf16x8*)(Bs + (wn * 64 + n * 16 + l16) * 32 + g * 8);
    #pragma unroll
    for (int m = 0; m < 4; ++m)
      #pragma unroll
      for (int n = 0; n < 4; ++n)
        acc[m][n] = __builtin_amdgcn_mfma_f32_16x16x32_bf16(af[m], bfv[n], acc[m][n], 0, 0, 0);
    __syncthreads();
  }
  const long cz = (long)blockIdx.z * sC;
  if (outBf16) {
    u16* C = (u16*)Cout;
    #pragma unroll
    for (int m = 0; m < 4; ++m) {
      const long row = m0 + wm * 64 + m * 16 + g * 4;
      #pragma unroll
      for (int n = 0; n < 4; ++n) {
        const long col = n0 + wn * 64 + n * 16 + l16;
        if (col < N) {
          #pragma unroll
          for (int r = 0; r < 4; ++r) C[cz + (row + r) * ldc + col] = f2bf(acc[m][n][r]);
        }
      }
    }
  } else {
    float* C = (float*)Cout;
    #pragma unroll
    for (int m = 0; m < 4; ++m) {
      const long row = m0 + wm * 64 + m * 16 + g * 4;
      #pragma unroll
      for (int n = 0; n < 4; ++n) {
        const long col = n0 + wn * 64 + n * 16 + l16;
        if (col < N) {
          #pragma unroll
          for (int r = 0; r < 4; ++r) C[cz + (row + r) * ldc + col] = acc[m][n][r];
        }
      }
    }
  }
}

// ---------- f32-accurate C = A * B^T via f16 pair split (3 MFMA / tile) ----------
__global__ __launch_bounds__(256) void k_gemm_f16pair(
    const f16* __restrict__ Ah, const f16* __restrict__ Al,
    const f16* __restrict__ Bh, const f16* __restrict__ Bl,
    float* __restrict__ C, int N, int K, long lda, long ldb, long ldc) {
  const long m0 = (long)blockIdx.y * 128;
  const long n0 = (long)blockIdx.x * 128;
  __shared__ __align__(16) f16 AhS[4096], AlS[4096], BhS[4096], BlS[4096];
  const int tid = threadIdx.x;
  const int lane = tid & 63, wid = tid >> 6;
  const int g = lane >> 4, l16 = lane & 15;
  const int srow = tid >> 2;
  const int scol = (tid & 3) * 8;
  const int wm = wid >> 1, wn = wid & 1;
  f32x4 a0[4][4], a1[4][4];
  #pragma unroll
  for (int m = 0; m < 4; ++m)
    #pragma unroll
    for (int n = 0; n < 4; ++n) { a0[m][n] = (f32x4){0.f,0.f,0.f,0.f}; a1[m][n] = (f32x4){0.f,0.f,0.f,0.f}; }
  for (int k0 = 0; k0 < K; k0 += 32) {
    long rb0 = n0 + srow; if (rb0 >= N) rb0 = 0;
    long rb1 = n0 + 64 + srow; if (rb1 >= N) rb1 = 0;
    glds16(Ah + (m0 + srow) * lda + k0 + scol, AhS + (size_t)wid * 512);
    glds16(Ah + (m0 + 64 + srow) * lda + k0 + scol, AhS + 2048 + (size_t)wid * 512);
    glds16(Al + (m0 + srow) * lda + k0 + scol, AlS + (size_t)wid * 512);
    glds16(Al + (m0 + 64 + srow) * lda + k0 + scol, AlS + 2048 + (size_t)wid * 512);
    glds16(Bh + rb0 * ldb + k0 + scol, BhS + (size_t)wid * 512);
    glds16(Bh + rb1 * ldb + k0 + scol, BhS + 2048 + (size_t)wid * 512);
    glds16(Bl + rb0 * ldb + k0 + scol, BlS + (size_t)wid * 512);
    glds16(Bl + rb1 * ldb + k0 + scol, BlS + 2048 + (size_t)wid * 512);
    __syncthreads();
    f16x8 ah[4], al[4];
    #pragma unroll
    for (int m = 0; m < 4; ++m) {
      ah[m] = *(const f16x8*)(AhS + (wm * 64 + m * 16 + l16) * 32 + g * 8);
      al[m] = *(const f16x8*)(AlS + (wm * 64 + m * 16 + l16) * 32 + g * 8);
    }
    #pragma unroll
    for (int n = 0; n < 4; ++n) {
      f16x8 bh = *(const f16x8*)(BhS + (wn * 64 + n * 16 + l16) * 32 + g * 8);
      f16x8 bl = *(const f16x8*)(BlS + (wn * 64 + n * 16 + l16) * 32 + g * 8);
      #pragma unroll
      for (int m = 0; m < 4; ++m) {
        a0[m][n] = __builtin_amdgcn_mfma_f32_16x16x32_f16(ah[m], bh, a0[m][n], 0, 0, 0);
        a1[m][n] = __builtin_amdgcn_mfma_f32_16x16x32_f16(ah[m], bl, a1[m][n], 0, 0, 0);
        a1[m][n] = __builtin_amdgcn_mfma_f32_16x16x32_f16(al[m], bh, a1[m][n], 0, 0, 0);
      }
    }
    __syncthreads();
  }
  #pragma unroll
  for (int m = 0; m < 4; ++m) {
    const long row = m0 + wm * 64 + m * 16 + g * 4;
    #pragma unroll
    for (int n = 0; n < 4; ++n) {
      const long col = n0 + wn * 64 + n * 16 + l16;
      if (col < N) {
        #pragma unroll
        for (int r = 0; r < 4; ++r)
          C[(row + r) * ldc + col] = a0[m][n][r] + a1[m][n][r] * 4.8828125e-4f;
      }
    }
  }
}

// ---------- per-row post kernels ----------
__global__ __launch_bounds__(256) void k_rms_qr(float* __restrict__ qr, const float* __restrict__ w,
    f16* __restrict__ qh, f16* __restrict__ ql, u16* __restrict__ qb) {
  const int row = blockIdx.x, tid = threadIdx.x;
  float v[3];
  float ss = 0.f;
  #pragma unroll
  for (int i = 0; i < 3; ++i) { v[i] = qr[(long)row * 768 + tid + i * 256]; ss += v[i] * v[i]; }
  #pragma unroll
  for (int m = 1; m < 64; m <<= 1) ss += __shfl_xor(ss, m, 64);
  __shared__ float wsum[4];
  if ((tid & 63) == 0) wsum[tid >> 6] = ss;
  __syncthreads();
  float tot = wsum[0] + wsum[1] + wsum[2] + wsum[3];
  float gsc = 1.0f / sqrtf(tot * (1.0f / 768.0f) + 1e-6f);
  #pragma unroll
  for (int i = 0; i < 3; ++i) {
    long o = (long)row * 768 + tid + i * 256;
    float y = v[i] * gsc * w[tid + i * 256];
    qr[o] = y;
    f16 hh = (f16)y;
    qh[o] = hh;
    ql[o] = (f16)((y - (float)hh) * 2048.0f);
    qb[o] = f2bf(y);
  }
}

__global__ __launch_bounds__(256) void k_kvpost(const float* __restrict__ kvraw, const float* __restrict__ w,
    const float* __restrict__ cosb, const float* __restrict__ sinb,
    u16* __restrict__ kvc, u16* __restrict__ kpe) {
  const int row = blockIdx.x, tid = threadIdx.x;
  const int s = row & 2047;
  float v0 = kvraw[(long)row * 576 + tid];
  float v1 = kvraw[(long)row * 576 + 256 + tid];
  float ss = v0 * v0 + v1 * v1;
  #pragma unroll
  for (int m = 1; m < 64; m <<= 1) ss += __shfl_xor(ss, m, 64);
  __shared__ float wsum[4];
  if ((tid & 63) == 0) wsum[tid >> 6] = ss;
  __syncthreads();
  float tot = wsum[0] + wsum[1] + wsum[2] + wsum[3];
  float gsc = 1.0f / sqrtf(tot * (1.0f / 512.0f) + 1e-6f);
  kvc[(long)row * 512 + tid] = f2bf(v0 * gsc * w[tid]);
  kvc[(long)row * 512 + 256 + tid] = f2bf(v1 * gsc * w[256 + tid]);
  if (tid < 32) {
    float x1 = kvraw[(long)row * 576 + 512 + tid];
    float x2 = kvraw[(long)row * 576 + 544 + tid];
    float c = cosb[s * 32 + tid], sn = sinb[s * 32 + tid];
    kpe[(long)row * 64 + tid] = f2bf(x1 * c - x2 * sn);
    kpe[(long)row * 64 + 32 + tid] = f2bf(x1 * sn + x2 * c);
  }
}

__global__ __launch_bounds__(256) void k_qpost(const float* __restrict__ q,
    const float* __restrict__ cosb, const float* __restrict__ sinb,
    u16* __restrict__ qn, u16* __restrict__ qpe) {
  const int row = blockIdx.x, tid = threadIdx.x;
  const int s = row & 2047;
  const long qb = (long)row * 3072;
  #pragma unroll
  for (int i = 0; i < 8; ++i) {
    int idx = tid + i * 256;
    int h = idx >> 7, d = idx & 127;
    qn[(long)row * 2048 + idx] = f2bf(q[qb + h * 192 + d]);
  }
  #pragma unroll
  for (int i = 0; i < 2; ++i) {
    int p = tid + i * 256;
    int h = p >> 5, e = p & 31;
    float x1 = q[qb + h * 192 + 128 + e];
    float x2 = q[qb + h * 192 + 160 + e];
    float c = cosb[s * 32 + e], sn = sinb[s * 32 + e];
    qpe[(long)row * 1024 + h * 64 + e] = f2bf(x1 * c - x2 * sn);
    qpe[(long)row * 1024 + h * 64 + 32 + e] = f2bf(x1 * sn + x2 * c);
  }
}

__global__ __launch_bounds__(256) void k_idxqpost(const float* __restrict__ iq,
    const float* __restrict__ cosb, const float* __restrict__ sinb,
    f16* __restrict__ oh, f16* __restrict__ ol) {
  const int row = blockIdx.x, tid = threadIdx.x;
  const int s = row & 2047;
  const long ib = (long)row * 2048;
  #pragma unroll
  for (int i = 0; i < 2; ++i) {
    int p = tid + i * 256;
    int h = p >> 5, e = p & 31;
    float x1 = iq[ib + h * 128 + e], x2 = iq[ib + h * 128 + 32 + e];
    float c = cosb[s * 32 + e], sn = sinb[s * 32 + e];
    wsplit(oh, ol, idxq_off(row, h, e), x1 * c - x2 * sn);
    wsplit(oh, ol, idxq_off(row, h, e + 32), x1 * sn + x2 * c);
  }
  #pragma unroll
  for (int i = 0; i < 4; ++i) {
    int idx = tid + i * 256;
    int h = idx >> 6, e2 = idx & 63;
    int c = 64 + e2;
    wsplit(oh, ol, idxq_off(row, h, c), iq[ib + h * 128 + c]);
  }
}

__global__ __launch_bounds__(128) void k_idxkpost(const float* __restrict__ ik,
    const float* __restrict__ w, const float* __restrict__ bb,
    const float* __restrict__ cosb, const float* __restrict__ sinb,
    f16* __restrict__ oh, f16* __restrict__ ol) {
  const int row = blockIdx.x, tid = threadIdx.x;
  const int s = row & 2047;
  float v = ik[(long)row * 128 + tid];
  float sum = v;
  #pragma unroll
  for (int m = 1; m < 64; m <<= 1) sum += __shfl_xor(sum, m, 64);
  __shared__ float r0[2], r1[2];
  __shared__ float ybuf[128];
  if ((tid & 63) == 0) r0[tid >> 6] = sum;
  __syncthreads();
  float mean = (r0[0] + r0[1]) * (1.0f / 128.0f);
  float d = v - mean;
  float s2 = d * d;
  #pragma unroll
  for (int m = 1; m < 64; m <<= 1) s2 += __shfl_xor(s2, m, 64);
  if ((tid & 63) == 0) r1[tid >> 6] = s2;
  __syncthreads();
  float var = (r1[0] + r1[1]) * (1.0f / 128.0f);
  float y = d * (1.0f / sqrtf(var + 1e-6f)) * w[tid] + bb[tid];
  ybuf[tid] = y;
  __syncthreads();
  float outv = y;
  if (tid < 64) {
    int e = tid & 31;
    float x1 = ybuf[e], x2 = ybuf[32 + e];
    float c = cosb[s * 32 + e], sn = sinb[s * 32 + e];
    outv = (tid < 32) ? (x1 * c - x2 * sn) : (x1 * sn + x2 * c);
  }
  int csw = tid ^ ((row & 7) << 3);  // pre-swizzled for conflict-free LDS reads in k_iscore
  long o = (long)row * 128 + csw;
  f16 hh = (f16)outv;
  oh[o] = hh;
  ol[o] = (f16)((outv - (float)hh) * 2048.0f);
}

// idx weights projection (N=16), f32 exact
__global__ __launch_bounds__(256) void k_wproj(const float* __restrict__ x,
    const float* __restrict__ proj, float* __restrict__ out) {
  const int row = blockIdx.x, tid = threadIdx.x;
  __shared__ float xr[2048];
  #pragma unroll
  for (int i = 0; i < 8; ++i) xr[tid + i * 256] = x[(long)row * 2048 + tid + i * 256];
  __syncthreads();
  int h = tid >> 4, seg = tid & 15;
  float acc = 0.f;
  for (int k = 0; k < 128; ++k) acc += xr[seg * 128 + k] * proj[h * 2048 + seg * 128 + k];
  #pragma unroll
  for (int m = 1; m < 16; m <<= 1) acc += __shfl_xor(acc, m, 64);
  if (seg == 0) out[(long)row * 16 + h] = acc * 0.25f * 0.08838834764831843f;
}

// ---------- indexer scores: sum_h relu(q_h . k) * w_h, f32-accurate ----------
__global__ __launch_bounds__(256) void k_iscore(
    const f16* __restrict__ Ah, const f16* __restrict__ Al,   // idx_q frag layout
    const f16* __restrict__ Bh, const f16* __restrict__ Bl,   // idx_k swizzled
    const float* __restrict__ wts, float* __restrict__ out) {
  const int b = blockIdx.z;
  const int s0 = blockIdx.y * 64, t0 = blockIdx.x * 128;
  if (t0 > s0 + 63) return;
  __shared__ __align__(16) f16 BhS[128 * 128];
  __shared__ __align__(16) f16 BlS[128 * 128];
  const int tid = threadIdx.x;
  const int lane = tid & 63, wid = tid >> 6;
  const int g = lane >> 4, l16 = lane & 15;
  const long brow = ((long)b * 2048 + t0) * 128;
  #pragma unroll
  for (int c = 0; c < 8; ++c) {
    int row = c * 16 + (tid >> 4);
    int col = (tid & 15) * 8;
    glds16(Bh + brow + (long)row * 128 + col, BhS + (size_t)c * 2048 + (size_t)wid * 512);
    glds16(Bl + brow + (long)row * 128 + col, BlS + (size_t)c * 2048 + (size_t)wid * 512);
  }
  __syncthreads();
  const int ws_ = wid >> 1, wt = wid & 1;
  f32x4 sc[2][4];
  #pragma unroll
  for (int m = 0; m < 2; ++m)
    #pragma unroll
    for (int n = 0; n < 4; ++n) sc[m][n] = (f32x4){0.f, 0.f, 0.f, 0.f};
  for (int h = 0; h < 16; ++h) {
    f16x8 ah[2][4], al[2][4];
    #pragma unroll
    for (int m = 0; m < 2; ++m) {
      int rt = (b * 2048 + s0 + ws_ * 32 + m * 16) >> 4;
      #pragma unroll
      for (int kc = 0; kc < 4; ++kc) {
        long o = ((((long)rt * 16 + h) * 4 + kc) * 4 + g) * 128 + l16 * 8;
        ah[m][kc] = *(const f16x8*)(Ah + o);
        al[m][kc] = *(const f16x8*)(Al + o);
      }
    }
    f32x4 l0[2][4], l1[2][4];
    #pragma unroll
    for (int m = 0; m < 2; ++m)
      #pragma unroll
      for (int n = 0; n < 4; ++n) { l0[m][n] = (f32x4){0.f,0.f,0.f,0.f}; l1[m][n] = (f32x4){0.f,0.f,0.f,0.f}; }
    #pragma unroll
    for (int kc = 0; kc < 4; ++kc) {
      #pragma unroll
      for (int n = 0; n < 4; ++n) {
        int row = wt * 64 + n * 16 + l16;
        int ecol = (kc * 32 + g * 8) ^ ((row & 7) * 8);
        f16x8 bh = *(const f16x8*)(BhS + row * 128 + ecol);
        f16x8 bl = *(const f16x8*)(BlS + row * 128 + ecol);
        #pragma unroll
        for (int m = 0; m < 2; ++m) {
          l0[m][n] = __builtin_amdgcn_mfma_f32_16x16x32_f16(ah[m][kc], bh, l0[m][n], 0, 0, 0);
          l1[m][n] = __builtin_amdgcn_mfma_f32_16x16x32_f16(ah[m][kc], bl, l1[m][n], 0, 0, 0);
          l1[m][n] = __builtin_amdgcn_mfma_f32_16x16x32_f16(al[m][kc], bh, l1[m][n], 0, 0, 0);
        }
      }
    }
    #pragma unroll
    for (int m = 0; m < 2; ++m) {
      #pragma unroll
      for (int r = 0; r < 4; ++r) {
        float wv = wts[((long)b * 2048 + s0 + ws_ * 32 + m * 16 + g * 4 + r) * 16 + h];
        #pragma unroll
        for (int n = 0; n < 4; ++n) {
          float lg = l0[m][n][r] + l1[m][n][r] * 4.8828125e-4f;
          if (lg > 0.f) sc[m][n][r] += lg * wv;
        }
      }
    }
  }
  #pragma unroll
  for (int m = 0; m < 2; ++m) {
    #pragma unroll
    for (int n = 0; n < 4; ++n) {
      int tcol = t0 + wt * 64 + n * 16 + l16;
      #pragma unroll
      for (int r = 0; r < 4; ++r) {
        int srow = s0 + ws_ * 32 + m * 16 + g * 4 + r;
        out[((long)b * 2048 + srow) * 2048 + tcol] = sc[m][n][r];
      }
    }
  }
}

// ---------- exact top-512 (causal prefix only), ties -> ascending index ----------
__global__ __launch_bounds__(256) void k_topk(const float* __restrict__ scores, int* __restrict__ sel) {
  const int bs = blockIdx.x;
  const int s = bs & 2047;
  const int n = s + 1;
  const int tid = threadIdx.x;
  int* out = sel + (long)bs * 512;
  if (n <= 512) {
    for (int i = tid; i < 512; i += 256) out[i] = (i < n) ? i : -1;
    return;
  }
  const float* sr = scores + (long)bs * 2048;
  __shared__ u32 hist[256];
  __shared__ u32 sh_prefix;
  __shared__ int sh_R, sh_cnt, sh_tiebase;
  __shared__ int sh_wcnt[4];
  if (tid == 0) { sh_prefix = 0; sh_R = 512; }
  for (int pass = 0; pass < 4; ++pass) {
    int shift = 24 - pass * 8;
    for (int i = tid; i < 256; i += 256) hist[i] = 0;
    __syncthreads();
    u32 pfx = sh_prefix;
    int R = sh_R;
    for (int t = tid; t < n; t += 256) {
      u32 u = __builtin_bit_cast(u32, sr[t]);
      u = (u & 0x80000000u) ? ~u : (u | 0x80000000u);
      bool ok = (pass == 0) || ((u >> (shift + 8)) == (pfx >> (shift + 8)));
      if (ok) atomicAdd(&hist[(u >> shift) & 255], 1u);
    }
    __syncthreads();
    if (tid == 0) {
      int cum = 0, v = 255;
      for (; v >= 0; --v) {
        int c = (int)hist[v];
        if (cum + c >= R) break;
        cum += c;
      }
      sh_prefix = pfx | ((u32)v << shift);
      sh_R = R - cum;
    }
    __syncthreads();
  }
  const u32 thr = sh_prefix;
  const int R = sh_R;
  if (tid == 0) { sh_cnt = 0; sh_tiebase = 0; }
  __syncthreads();
  for (int t = tid; t < n; t += 256) {
    u32 u = __builtin_bit_cast(u32, sr[t]);
    u = (u & 0x80000000u) ? ~u : (u | 0x80000000u);
    if (u > thr) out[atomicAdd(&sh_cnt, 1)] = t;
  }
  __syncthreads();
  const int base = sh_cnt;  // == 512 - R
  for (int c0 = 0; c0 < n; c0 += 256) {
    int t = c0 + tid;
    bool f = false;
    if (t < n) {
      u32 u = __builtin_bit_cast(u32, sr[t]);
      u = (u & 0x80000000u) ? ~u : (u | 0x80000000u);
      f = (u == thr);
    }
    unsigned long long mk = __ballot(f);
    int lane = tid & 63, w = tid >> 6;
    int rank = __popcll(mk & ((1ull << lane) - 1ull));
    if (lane == 0) sh_wcnt[w] = __popcll(mk);
    __syncthreads();
    int wbase = 0;
    for (int i = 0; i < w; ++i) wbase += sh_wcnt[i];
    int tb = sh_tiebase;
    if (f) {
      int pos = tb + wbase + rank;
      if (pos < R) out[base + pos] = t;
    }
    __syncthreads();
    if (tid == 0) sh_tiebase = tb + sh_wcnt[0] + sh_wcnt[1] + sh_wcnt[2] + sh_wcnt[3];
    __syncthreads();
  }
}

// ---------- sparse attention over selected keys ----------
#define KSTR 584
__global__ __launch_bounds__(256) void k_attn(
    const int* __restrict__ sel, const u16* __restrict__ qabs, const u16* __restrict__ qpe,
    const u16* __restrict__ kvc, const u16* __restrict__ kpe, u16* __restrict__ oc) {
  const int bs = blockIdx.x;
  const int b = bs >> 11;
  const int tid = threadIdx.x;
  const int lane = tid & 63, wid = tid >> 6;
  const int g = lane >> 4, l16 = lane & 15;
  __shared__ __align__(16) u16 K_lds[32 * KSTR];
  __shared__ float S_lds[2 * 16 * 36];
  __shared__ __align__(16) u16 P_lds[16 * 40];
  __shared__ int t_tile[32];
  __shared__ float m_lds[16], l_lds[16], f_lds[16];
  if (tid < 16) { m_lds[tid] = -3e38f; l_lds[tid] = 0.f; }
  const int half = wid >> 1, jhalf = wid & 1;
  const int kcb = half * 9;
  bf16x8 qf[9];
  #pragma unroll
  for (int i = 0; i < 9; ++i) {
    int kc = kcb + i;
    if (kc < 16) qf[i] = *(const bf16x8*)(qabs + ((long)bs * 16 + l16) * 512 + kc * 32 + g * 8);
    else qf[i] = *(const bf16x8*)(qpe + ((long)bs * 16 + l16) * 64 + (kc - 16) * 32 + g * 8);
  }
  f32x4 oacc[8];
  #pragma unroll
  for (int cf = 0; cf < 8; ++cf) oacc[cf] = (f32x4){0.f, 0.f, 0.f, 0.f};
  __syncthreads();
  for (int jt = 0; jt < 16; ++jt) {
    // gather 32 selected rows (kvc 512 + kpe 64) into LDS
    #pragma unroll
    for (int it = 0; it < 2; ++it) {
      int cid = it * 256 + tid;
      if (cid < 288) {
        int jr = cid / 9, part = cid % 9;
        int t = sel[(long)bs * 512 + jt * 32 + jr];
        if (part == 0) t_tile[jr] = t;
        int te = t < 0 ? 0 : t;
        const u16* src = (part < 8) ? (kvc + ((long)(b * 2048 + te)) * 512 + part * 64)
                                    : (kpe + ((long)(b * 2048 + te)) * 64);
        uint4* dst = (uint4*)&K_lds[jr * KSTR + part * 64];
        const uint4* s4 = (const uint4*)src;
        #pragma unroll
        for (int i = 0; i < 8; ++i) dst[i] = s4[i];
      }
    }
    __syncthreads();
    // QK^T (each wave: 16 j of this tile's 32, half of K)
    f32x4 sacc = (f32x4){0.f, 0.f, 0.f, 0.f};
    #pragma unroll
    for (int i = 0; i < 9; ++i) {
      int kc = kcb + i;
      bf16x8 bfr = *(const bf16x8*)&K_lds[(jhalf * 16 + l16) * KSTR + kc * 32 + g * 8];
      sacc = __builtin_amdgcn_mfma_f32_16x16x32_bf16(qf[i], bfr, sacc, 0, 0, 0);
    }
    int jloc = jhalf * 16 + l16;
    int tj = t_tile[jloc];
    #pragma unroll
    for (int r = 0; r < 4; ++r) {
      int h = g * 4 + r;
      S_lds[half * 576 + h * 36 + jloc] = (tj < 0) ? -1e30f : sacc[r] * 0.07216878364870322f;
    }
    __syncthreads();
    // online softmax update
    {
      int h = tid >> 4, q16 = tid & 15;
      float vs[2];
      float mx = -3e38f;
      #pragma unroll
      for (int k = 0; k < 2; ++k) {
        int j = q16 + k * 16;
        vs[k] = S_lds[h * 36 + j] + S_lds[576 + h * 36 + j];
        mx = fmaxf(mx, vs[k]);
      }
      #pragma unroll
      for (int m = 1; m < 16; m <<= 1) mx = fmaxf(mx, __shfl_xor(mx, m, 64));
      float m_old = m_lds[h];
      float m_new = fmaxf(m_old, mx);
      float ps = 0.f;
      #pragma unroll
      for (int k = 0; k < 2; ++k) {
        float p = __expf(vs[k] - m_new);
        ps += p;
        P_lds[h * 40 + q16 + k * 16] = f2bf(p);
      }
      #pragma unroll
      for (int m = 1; m < 16; m <<= 1) ps += __shfl_xor(ps, m, 64);
      if (q16 == 0) {
        float f = __expf(m_old - m_new);
        f_lds[h] = f;
        m_lds[h] = m_new;
        l_lds[h] = l_lds[h] * f + ps;
      }
    }
    __syncthreads();
    // rescale + PV
    float fr[4];
    #pragma unroll
    for (int r = 0; r < 4; ++r) fr[r] = f_lds[g * 4 + r];
    #pragma unroll
    for (int cf = 0; cf < 8; ++cf)
      #pragma unroll
      for (int r = 0; r < 4; ++r) oacc[cf][r] *= fr[r];
    bf16x8 pa = *(const bf16x8*)&P_lds[l16 * 40 + g * 8];
    #pragma unroll
    for (int cf = 0; cf < 8; ++cf) {
      int col = wid * 128 + cf * 16 + l16;
      bf16x8 vb;
      #pragma unroll
      for (int e = 0; e < 8; ++e) vb[e] = (short)K_lds[(g * 8 + e) * KSTR + col];
      oacc[cf] = __builtin_amdgcn_mfma_f32_16x16x32_bf16(pa, vb, oacc[cf], 0, 0, 0);
    }
    __syncthreads();
  }
  float li[4];
  #pragma unroll
  for (int r = 0; r < 4; ++r) li[r] = 1.0f / l_lds[g * 4 + r];
  #pragma unroll
  for (int cf = 0; cf < 8; ++cf) {
    int col = wid * 128 + cf * 16 + l16;
    #pragma unroll
    for (int r = 0; r < 4; ++r) {
      int h = g * 4 + r;
      oc[((long)bs * 16 + h) * 512 + col] = f2bf(oacc[cf][r] * li[r]);
    }
  }
}

// ---------- launcher ----------
extern "C" void kernel_launch(void* const* d_in, const int* in_sizes, int n_in,
                              void* d_out, int out_size, void* d_ws, size_t ws_size,
                              hipStream_t stream) {
  const float* x = (const float*)d_in[0];
  const float* fcos = (const float*)d_in[1];
  const float* fsin = (const float*)d_in[2];
  const float* wq_a = (const float*)d_in[4];
  const float* q_norm_w = (const float*)d_in[5];
  const float* wq_b = (const float*)d_in[6];
  const float* wkv_a = (const float*)d_in[7];
  const float* kv_norm_w = (const float*)d_in[8];
  const float* wkv_b = (const float*)d_in[9];
  const float* wo = (const float*)d_in[10];
  const float* idx_wq_b = (const float*)d_in[11];
  const float* idx_wk = (const float*)d_in[12];
  const float* iknw = (const float*)d_in[13];
  const float* iknb = (const float*)d_in[14];
  const float* iwp = (const float*)d_in[15];

  size_t off = 0;
  char* wsb = (char*)d_ws;
  auto alloc = [&](size_t bytes) -> char* {
    char* p = wsb + off;
    off += (bytes + 255) & ~(size_t)255;
    return p;
  };
  // ~268 MB total workspace
  u16* x_b16  = (u16*)alloc(16777216);
  f16* xh     = (f16*)alloc(16777216);
  f16* xl     = (f16*)alloc(16777216);
  f16* wqa_h  = (f16*)alloc(3145728);
  f16* wqa_l  = (f16*)alloc(3145728);
  float* qr   = (float*)alloc(12582912);
  f16* qr_h   = (f16*)alloc(6291456);
  f16* qr_l   = (f16*)alloc(6291456);
  u16* qr_b   = (u16*)alloc(6291456);
  u16* wqb_b  = (u16*)alloc(4718592);
  char* QBIG  = alloc(50331648);          // q f32 -> idxq f32 -> scores f32 -> o_c bf16
  u16* qn_b   = (u16*)alloc(16777216);
  u16* qpe_b  = (u16*)alloc(8388608);
  u16* wkva_b = (u16*)alloc(2359296);
  float* kvraw= (float*)alloc(9437184);
  u16* kvc_b  = (u16*)alloc(4194304);
  u16* kpe_b  = (u16*)alloc(524288);
  u16* wkvb_b = (u16*)alloc(4194304);
  u16* wkvbnt = (u16*)alloc(2097152);
  u16* wo_b   = (u16*)alloc(8388608);
  f16* iwqb_h = (f16*)alloc(3145728);
  f16* iwqb_l = (f16*)alloc(3145728);
  f16* idxq_h = (f16*)alloc(16777216);
  f16* idxq_l = (f16*)alloc(16777216);
  f16* iwk_h  = (f16*)alloc(524288);
  f16* iwk_l  = (f16*)alloc(524288);
  float* idxk_f = (float*)alloc(2097152);
  f16* idxk_h = (f16*)alloc(1048576);
  f16* idxk_l = (f16*)alloc(1048576);
  float* idxw = (float*)alloc(262144);
  int* sel    = (int*)alloc(8388608);
  // aliases (lifetime-disjoint)
  u16* q_abs  = (u16*)xh;                 // xh+xl region (33.5MB), used after last xh/xl read
  float* q_f32 = (float*)QBIG;
  float* idxq_f32 = (float*)QBIG;
  float* scores = (float*)QBIG;
  u16* o_c    = (u16*)QBIG;
  u16* o_d    = (u16*)idxq_h;

  // 1. conversions / splits
  k_cvt_bf16<<<8192, 256, 0, stream>>>(x, x_b16, 8388608L);
  k_split<<<8192, 256, 0, stream>>>(x, xh, xl, 8388608L);
  k_split<<<1536, 256, 0, stream>>>(wq_a, wqa_h, wqa_l, 1572864L);
  k_cvt_bf16<<<2304, 256, 0, stream>>>(wq_b, wqb_b, 2359296L);
  k_cvt_bf16<<<1152, 256, 0, stream>>>(wkv_a, wkva_b, 1179648L);
  k_cvt_wkvb<<<8192, 256, 0, stream>>>(wkv_b, wkvb_b, wkvbnt);
  k_cvt_bf16<<<4096, 256, 0, stream>>>(wo, wo_b, 4194304L);
  k_split<<<1536, 256, 0, stream>>>(idx_wq_b, iwqb_h, iwqb_l, 1572864L);
  k_split<<<256, 256, 0, stream>>>(idx_wk, iwk_h, iwk_l, 262144L);

  // 2. qr = rmsnorm(x @ wq_a.T)  [f32-accurate]
  k_gemm_f16pair<<<dim3(6, 32, 1), 256, 0, stream>>>(xh, xl, wqa_h, wqa_l, qr, 768, 2048, 2048, 2048, 768);
  k_rms_qr<<<4096, 256, 0, stream>>>(qr, q_norm_w, qr_h, qr_l, qr_b);

  // 3. q = qr @ wq_b.T  (bf16 ok) ; rope/split
  k_gemm_bt<<<dim3(24, 32, 1), 256, 0, stream>>>(qr_b, wqb_b, QBIG, 3072, 768, 768, 768, 3072, 0, 0, 0, 0);
  k_qpost<<<4096, 256, 0, stream>>>(q_f32, fcos, fsin, qn_b, qpe_b);

  // 4. kv = x @ wkv_a.T ; rms + rope
  k_gemm_bt<<<dim3(5, 32, 1), 256, 0, stream>>>(x_b16, wkva_b, kvraw, 576, 2048, 2048, 2048, 576, 0, 0, 0, 0);
  k_kvpost<<<4096, 256, 0, stream>>>(kvraw, kv_norm_w, fcos, fsin, kvc_b, kpe_b);

  // 5. indexer q/k/w  [f32-accurate]
  k_gemm_f16pair<<<dim3(16, 32, 1), 256, 0, stream>>>(qr_h, qr_l, iwqb_h, iwqb_l, idxq_f32, 2048, 768, 768, 768, 2048);
  k_idxqpost<<<4096, 256, 0, stream>>>(idxq_f32, fcos, fsin, idxq_h, idxq_l);
  k_gemm_f16pair<<<dim3(1, 32, 1), 256, 0, stream>>>(xh, xl, iwk_h, iwk_l, idxk_f, 128, 2048, 2048, 2048, 128);
  k_idxkpost<<<4096, 128, 0, stream>>>(idxk_f, iknw, iknb, fcos, fsin, idxk_h, idxk_l);
  k_wproj<<<4096, 256, 0, stream>>>(x, iwp, idxw);

  // 6. q_abs per head (after last use of xh/xl; writes over them)
  k_gemm_bt<<<dim3(4, 32, 16), 256, 0, stream>>>(qn_b, wkvbnt, q_abs, 512, 128, 2048, 128, 8192, 128, 65536, 512, 1);

  // 7. indexer scores (causal tiles) + exact top-512
  k_iscore<<<dim3(16, 32, 2), 256, 0, stream>>>(idxq_h, idxq_l, idxk_h, idxk_l, idxw, scores);
  k_topk<<<4096, 256, 0, stream>>>(scores, sel);

  // 8. sparse attention -> o_c  (overwrites scores region)
  k_attn<<<4096, 256, 0, stream>>>(sel, q_abs, qpe_b, kvc_b, kpe_b, o_c);

  // 9. o_d = per-head o_c @ wkv_b3[:,128:,:]  then  out = o_d @ wo.T
  k_gemm_bt<<<dim3(1, 32, 16), 256, 0, stream>>>(o_c, wkvb_b + 65536, o_d, 128, 512, 8192, 512, 2048, 512, 131072, 128, 1);
  k_gemm_bt<<<dim3(16, 32, 1), 256, 0, stream>>>(o_d, wo_b, d_out, 2048, 2048, 2048, 2048, 2048, 0, 0, 0, 0);
}

// Round 3
// 1532.030 us; speedup vs baseline: 1.0077x; 1.0077x over previous
//
#include <hip/hip_runtime.h>

typedef short bf16x8 __attribute__((ext_vector_type(8)));
typedef _Float16 f16x8 __attribute__((ext_vector_type(8)));
typedef float f32x4 __attribute__((ext_vector_type(4)));
typedef _Float16 f16;
typedef unsigned short u16;
typedef unsigned int u32;

#define DEVFN static __device__ __forceinline__

// ---------- helpers ----------
DEVFN u16 f2bf(float f) {
  u32 u = __builtin_bit_cast(u32, f);
  return (u16)((u + 0x7FFFu + ((u >> 16) & 1u)) >> 16);
}

DEVFN void glds16(const void* g, void* l) {
  __builtin_amdgcn_global_load_lds((const __attribute__((address_space(1))) void*)g,
                                   (__attribute__((address_space(3))) void*)l, 16, 0, 0);
}

DEVFN void wsplit(f16* oh, f16* ol, long o, float v) {
  f16 hh = (f16)v;
  oh[o] = hh;
  ol[o] = (f16)((v - (float)hh) * 2048.0f);
}

// idx_q fragment-friendly layout: [row/16][h][kc][g][ri][8]
DEVFN long idxq_off(int row, int h, int c) {
  return ((((long)(row >> 4) * 16 + h) * 4 + (c >> 5)) * 4 + ((c >> 3) & 3)) * 128
         + (long)(row & 15) * 8 + (c & 7);
}

// ---------- elementwise conversions ----------
__global__ __launch_bounds__(256) void k_cvt_bf16(const float* __restrict__ in, u16* __restrict__ out, long n) {
  long i = ((long)blockIdx.x * 256 + threadIdx.x) * 4;
  if (i < n) {
    float4 v = *(const float4*)(in + i);
    out[i] = f2bf(v.x); out[i + 1] = f2bf(v.y); out[i + 2] = f2bf(v.z); out[i + 3] = f2bf(v.w);
  }
}

__global__ __launch_bounds__(256) void k_split(const float* __restrict__ in, f16* __restrict__ oh, f16* __restrict__ ol, long n) {
  long i = ((long)blockIdx.x * 256 + threadIdx.x) * 4;
  if (i < n) {
    float4 v = *(const float4*)(in + i);
    float a[4] = {v.x, v.y, v.z, v.w};
    #pragma unroll
    for (int k = 0; k < 4; ++k) {
      f16 hh = (f16)a[k];
      oh[i + k] = hh;
      ol[i + k] = (f16)((a[k] - (float)hh) * 2048.0f);
    }
  }
}

// fused: x -> bf16 copy + f16 split (single read of x)
__global__ __launch_bounds__(256) void k_cvt_split_x(const float* __restrict__ in, u16* __restrict__ ob,
    f16* __restrict__ oh, f16* __restrict__ ol, long n) {
  long i = ((long)blockIdx.x * 256 + threadIdx.x) * 4;
  if (i < n) {
    float4 v = *(const float4*)(in + i);
    float a[4] = {v.x, v.y, v.z, v.w};
    #pragma unroll
    for (int k = 0; k < 4; ++k) {
      ob[i + k] = f2bf(a[k]);
      f16 hh = (f16)a[k];
      oh[i + k] = hh;
      ol[i + k] = (f16)((a[k] - (float)hh) * 2048.0f);
    }
  }
}

// wkv_b -> full bf16 copy + transposed nope part [h][c][d]
__global__ __launch_bounds__(256) void k_cvt_wkvb(const float* __restrict__ wkvb, u16* __restrict__ full_b, u16* __restrict__ nope_t) {
  long i = (long)blockIdx.x * 256 + threadIdx.x;
  if (i >= 2097152) return;
  float v = wkvb[i];
  u16 bv = f2bf(v);
  full_b[i] = bv;
  long row = i >> 9;
  int c = (int)(i & 511);
  int h = (int)(row >> 8);
  int d = (int)(row & 255);
  if (d < 128) nope_t[(long)h * 65536 + (long)c * 128 + d] = bv;
}

// ---------- generic C = A * B^T, bf16 MFMA, 128x128 tile ----------
__global__ __launch_bounds__(256) void k_gemm_bt(
    const u16* __restrict__ A, const u16* __restrict__ B, void* __restrict__ Cout,
    int N, int K, long lda, long ldb, long ldc, long sA, long sB, long sC, int outBf16) {
  A += (long)blockIdx.z * sA;
  B += (long)blockIdx.z * sB;
  const long m0 = (long)blockIdx.y * 128;
  const long n0 = (long)blockIdx.x * 128;
  __shared__ __align__(16) u16 As[128 * 32];
  __shared__ __align__(16) u16 Bs[128 * 32];
  const int tid = threadIdx.x;
  const int lane = tid & 63, wid = tid >> 6;
  const int g = lane >> 4, l16 = lane & 15;
  const int srow = tid >> 2;
  const int scol = (tid & 3) * 8;
  const int wm = wid >> 1, wn = wid & 1;
  f32x4 acc[4][4];
  #pragma unroll
  for (int m = 0; m < 4; ++m)
    #pragma unroll
    for (int n = 0; n < 4; ++n) acc[m][n] = (f32x4){0.f, 0.f, 0.f, 0.f};
  for (int k0 = 0; k0 < K; k0 += 32) {
    long rb0 = n0 + srow; if (rb0 >= N) rb0 = 0;
    long rb1 = n0 + 64 + srow; if (rb1 >= N) rb1 = 0;
    glds16(A + (m0 + srow) * lda + k0 + scol, As + (size_t)wid * 512);
    glds16(A + (m0 + 64 + srow) * lda + k0 + scol, As + 2048 + (size_t)wid * 512);
    glds16(B + rb0 * ldb + k0 + scol, Bs + (size_t)wid * 512);
    glds16(B + rb1 * ldb + k0 + scol, Bs + 2048 + (size_t)wid * 512);
    __syncthreads();
    bf16x8 af[4], bfv[4];
    #pragma unroll
    for (int m = 0; m < 4; ++m) af[m] = *(const bf16x8*)(As + (wm * 64 + m * 16 + l16) * 32 + g * 8);
    #pragma unroll
    for (int n = 0; n < 4; ++n) bfv[n] = *(const bf16x8*)(Bs + (wn * 64 + n * 16 + l16) * 32 + g * 8);
    #pragma unroll
    for (int m = 0; m < 4; ++m)
      #pragma unroll
      for (int n = 0; n < 4; ++n)
        acc[m][n] = __builtin_amdgcn_mfma_f32_16x16x32_bf16(af[m], bfv[n], acc[m][n], 0, 0, 0);
    __syncthreads();
  }
  const long cz = (long)blockIdx.z * sC;
  if (outBf16) {
    u16* C = (u16*)Cout;
    #pragma unroll
    for (int m = 0; m < 4; ++m) {
      const long row = m0 + wm * 64 + m * 16 + g * 4;
      #pragma unroll
      for (int n = 0; n < 4; ++n) {
        const long col = n0 + wn * 64 + n * 16 + l16;
        if (col < N) {
          #pragma unroll
          for (int r = 0; r < 4; ++r) C[cz + (row + r) * ldc + col] = f2bf(acc[m][n][r]);
        }
      }
    }
  } else {
    float* C = (float*)Cout;
    #pragma unroll
    for (int m = 0; m < 4; ++m) {
      const long row = m0 + wm * 64 + m * 16 + g * 4;
      #pragma unroll
      for (int n = 0; n < 4; ++n) {
        const long col = n0 + wn * 64 + n * 16 + l16;
        if (col < N) {
          #pragma unroll
          for (int r = 0; r < 4; ++r) C[cz + (row + r) * ldc + col] = acc[m][n][r];
        }
      }
    }
  }
}

// ---------- f32-accurate C = A * B^T via f16 pair split (3 MFMA / tile) ----------
__global__ __launch_bounds__(256) void k_gemm_f16pair(
    const f16* __restrict__ Ah, const f16* __restrict__ Al,
    const f16* __restrict__ Bh, const f16* __restrict__ Bl,
    float* __restrict__ C, int N, int K, long lda, long ldb, long ldc) {
  const long m0 = (long)blockIdx.y * 128;
  const long n0 = (long)blockIdx.x * 128;
  __shared__ __align__(16) f16 AhS[4096], AlS[4096], BhS[4096], BlS[4096];
  const int tid = threadIdx.x;
  const int lane = tid & 63, wid = tid >> 6;
  const int g = lane >> 4, l16 = lane & 15;
  const int srow = tid >> 2;
  const int scol = (tid & 3) * 8;
  const int wm = wid >> 1, wn = wid & 1;
  f32x4 a0[4][4], a1[4][4];
  #pragma unroll
  for (int m = 0; m < 4; ++m)
    #pragma unroll
    for (int n = 0; n < 4; ++n) { a0[m][n] = (f32x4){0.f,0.f,0.f,0.f}; a1[m][n] = (f32x4){0.f,0.f,0.f,0.f}; }
  for (int k0 = 0; k0 < K; k0 += 32) {
    long rb0 = n0 + srow; if (rb0 >= N) rb0 = 0;
    long rb1 = n0 + 64 + srow; if (rb1 >= N) rb1 = 0;
    glds16(Ah + (m0 + srow) * lda + k0 + scol, AhS + (size_t)wid * 512);
    glds16(Ah + (m0 + 64 + srow) * lda + k0 + scol, AhS + 2048 + (size_t)wid * 512);
    glds16(Al + (m0 + srow) * lda + k0 + scol, AlS + (size_t)wid * 512);
    glds16(Al + (m0 + 64 + srow) * lda + k0 + scol, AlS + 2048 + (size_t)wid * 512);
    glds16(Bh + rb0 * ldb + k0 + scol, BhS + (size_t)wid * 512);
    glds16(Bh + rb1 * ldb + k0 + scol, BhS + 2048 + (size_t)wid * 512);
    glds16(Bl + rb0 * ldb + k0 + scol, BlS + (size_t)wid * 512);
    glds16(Bl + rb1 * ldb + k0 + scol, BlS + 2048 + (size_t)wid * 512);
    __syncthreads();
    f16x8 ah[4], al[4];
    #pragma unroll
    for (int m = 0; m < 4; ++m) {
      ah[m] = *(const f16x8*)(AhS + (wm * 64 + m * 16 + l16) * 32 + g * 8);
      al[m] = *(const f16x8*)(AlS + (wm * 64 + m * 16 + l16) * 32 + g * 8);
    }
    #pragma unroll
    for (int n = 0; n < 4; ++n) {
      f16x8 bh = *(const f16x8*)(BhS + (wn * 64 + n * 16 + l16) * 32 + g * 8);
      f16x8 bl = *(const f16x8*)(BlS + (wn * 64 + n * 16 + l16) * 32 + g * 8);
      #pragma unroll
      for (int m = 0; m < 4; ++m) {
        a0[m][n] = __builtin_amdgcn_mfma_f32_16x16x32_f16(ah[m], bh, a0[m][n], 0, 0, 0);
        a1[m][n] = __builtin_amdgcn_mfma_f32_16x16x32_f16(ah[m], bl, a1[m][n], 0, 0, 0);
        a1[m][n] = __builtin_amdgcn_mfma_f32_16x16x32_f16(al[m], bh, a1[m][n], 0, 0, 0);
      }
    }
    __syncthreads();
  }
  #pragma unroll
  for (int m = 0; m < 4; ++m) {
    const long row = m0 + wm * 64 + m * 16 + g * 4;
    #pragma unroll
    for (int n = 0; n < 4; ++n) {
      const long col = n0 + wn * 64 + n * 16 + l16;
      if (col < N) {
        #pragma unroll
        for (int r = 0; r < 4; ++r)
          C[(row + r) * ldc + col] = a0[m][n][r] + a1[m][n][r] * 4.8828125e-4f;
      }
    }
  }
}

// ---------- per-row post kernels ----------
__global__ __launch_bounds__(256) void k_rms_qr(float* __restrict__ qr, const float* __restrict__ w,
    f16* __restrict__ qh, f16* __restrict__ ql, u16* __restrict__ qb) {
  const int row = blockIdx.x, tid = threadIdx.x;
  float v[3];
  float ss = 0.f;
  #pragma unroll
  for (int i = 0; i < 3; ++i) { v[i] = qr[(long)row * 768 + tid + i * 256]; ss += v[i] * v[i]; }
  #pragma unroll
  for (int m = 1; m < 64; m <<= 1) ss += __shfl_xor(ss, m, 64);
  __shared__ float wsum[4];
  if ((tid & 63) == 0) wsum[tid >> 6] = ss;
  __syncthreads();
  float tot = wsum[0] + wsum[1] + wsum[2] + wsum[3];
  float gsc = 1.0f / sqrtf(tot * (1.0f / 768.0f) + 1e-6f);
  #pragma unroll
  for (int i = 0; i < 3; ++i) {
    long o = (long)row * 768 + tid + i * 256;
    float y = v[i] * gsc * w[tid + i * 256];
    qr[o] = y;
    f16 hh = (f16)y;
    qh[o] = hh;
    ql[o] = (f16)((y - (float)hh) * 2048.0f);
    qb[o] = f2bf(y);
  }
}

__global__ __launch_bounds__(256) void k_kvpost(const float* __restrict__ kvraw, const float* __restrict__ w,
    const float* __restrict__ cosb, const float* __restrict__ sinb,
    u16* __restrict__ kvc, u16* __restrict__ kpe) {
  const int row = blockIdx.x, tid = threadIdx.x;
  const int s = row & 2047;
  float v0 = kvraw[(long)row * 576 + tid];
  float v1 = kvraw[(long)row * 576 + 256 + tid];
  float ss = v0 * v0 + v1 * v1;
  #pragma unroll
  for (int m = 1; m < 64; m <<= 1) ss += __shfl_xor(ss, m, 64);
  __shared__ float wsum[4];
  if ((tid & 63) == 0) wsum[tid >> 6] = ss;
  __syncthreads();
  float tot = wsum[0] + wsum[1] + wsum[2] + wsum[3];
  float gsc = 1.0f / sqrtf(tot * (1.0f / 512.0f) + 1e-6f);
  kvc[(long)row * 512 + tid] = f2bf(v0 * gsc * w[tid]);
  kvc[(long)row * 512 + 256 + tid] = f2bf(v1 * gsc * w[256 + tid]);
  if (tid < 32) {
    float x1 = kvraw[(long)row * 576 + 512 + tid];
    float x2 = kvraw[(long)row * 576 + 544 + tid];
    float c = cosb[s * 32 + tid], sn = sinb[s * 32 + tid];
    kpe[(long)row * 64 + tid] = f2bf(x1 * c - x2 * sn);
    kpe[(long)row * 64 + 32 + tid] = f2bf(x1 * sn + x2 * c);
  }
}

__global__ __launch_bounds__(256) void k_qpost(const float* __restrict__ q,
    const float* __restrict__ cosb, const float* __restrict__ sinb,
    u16* __restrict__ qn, u16* __restrict__ qpe) {
  const int row = blockIdx.x, tid = threadIdx.x;
  const int s = row & 2047;
  const long qb = (long)row * 3072;
  #pragma unroll
  for (int i = 0; i < 8; ++i) {
    int idx = tid + i * 256;
    int h = idx >> 7, d = idx & 127;
    qn[(long)row * 2048 + idx] = f2bf(q[qb + h * 192 + d]);
  }
  #pragma unroll
  for (int i = 0; i < 2; ++i) {
    int p = tid + i * 256;
    int h = p >> 5, e = p & 31;
    float x1 = q[qb + h * 192 + 128 + e];
    float x2 = q[qb + h * 192 + 160 + e];
    float c = cosb[s * 32 + e], sn = sinb[s * 32 + e];
    qpe[(long)row * 1024 + h * 64 + e] = f2bf(x1 * c - x2 * sn);
    qpe[(long)row * 1024 + h * 64 + 32 + e] = f2bf(x1 * sn + x2 * c);
  }
}

__global__ __launch_bounds__(256) void k_idxqpost(const float* __restrict__ iq,
    const float* __restrict__ cosb, const float* __restrict__ sinb,
    f16* __restrict__ oh, f16* __restrict__ ol) {
  const int row = blockIdx.x, tid = threadIdx.x;
  const int s = row & 2047;
  const long ib = (long)row * 2048;
  #pragma unroll
  for (int i = 0; i < 2; ++i) {
    int p = tid + i * 256;
    int h = p >> 5, e = p & 31;
    float x1 = iq[ib + h * 128 + e], x2 = iq[ib + h * 128 + 32 + e];
    float c = cosb[s * 32 + e], sn = sinb[s * 32 + e];
    wsplit(oh, ol, idxq_off(row, h, e), x1 * c - x2 * sn);
    wsplit(oh, ol, idxq_off(row, h, e + 32), x1 * sn + x2 * c);
  }
  #pragma unroll
  for (int i = 0; i < 4; ++i) {
    int idx = tid + i * 256;
    int h = idx >> 6, e2 = idx & 63;
    int c = 64 + e2;
    wsplit(oh, ol, idxq_off(row, h, c), iq[ib + h * 128 + c]);
  }
}

__global__ __launch_bounds__(128) void k_idxkpost(const float* __restrict__ ik,
    const float* __restrict__ w, const float* __restrict__ bb,
    const float* __restrict__ cosb, const float* __restrict__ sinb,
    f16* __restrict__ oh, f16* __restrict__ ol) {
  const int row = blockIdx.x, tid = threadIdx.x;
  const int s = row & 2047;
  float v = ik[(long)row * 128 + tid];
  float sum = v;
  #pragma unroll
  for (int m = 1; m < 64; m <<= 1) sum += __shfl_xor(sum, m, 64);
  __shared__ float r0[2], r1[2];
  __shared__ float ybuf[128];
  if ((tid & 63) == 0) r0[tid >> 6] = sum;
  __syncthreads();
  float mean = (r0[0] + r0[1]) * (1.0f / 128.0f);
  float d = v - mean;
  float s2 = d * d;
  #pragma unroll
  for (int m = 1; m < 64; m <<= 1) s2 += __shfl_xor(s2, m, 64);
  if ((tid & 63) == 0) r1[tid >> 6] = s2;
  __syncthreads();
  float var = (r1[0] + r1[1]) * (1.0f / 128.0f);
  float y = d * (1.0f / sqrtf(var + 1e-6f)) * w[tid] + bb[tid];
  ybuf[tid] = y;
  __syncthreads();
  float outv = y;
  if (tid < 64) {
    int e = tid & 31;
    float x1 = ybuf[e], x2 = ybuf[32 + e];
    float c = cosb[s * 32 + e], sn = sinb[s * 32 + e];
    outv = (tid < 32) ? (x1 * c - x2 * sn) : (x1 * sn + x2 * c);
  }
  int csw = tid ^ ((row & 7) << 3);  // pre-swizzled for conflict-free LDS reads in k_iscore
  long o = (long)row * 128 + csw;
  f16 hh = (f16)outv;
  oh[o] = hh;
  ol[o] = (f16)((outv - (float)hh) * 2048.0f);
}

// idx weights projection (N=16), f32 exact
__global__ __launch_bounds__(256) void k_wproj(const float* __restrict__ x,
    const float* __restrict__ proj, float* __restrict__ out) {
  const int row = blockIdx.x, tid = threadIdx.x;
  __shared__ float xr[2048];
  #pragma unroll
  for (int i = 0; i < 8; ++i) xr[tid + i * 256] = x[(long)row * 2048 + tid + i * 256];
  __syncthreads();
  int h = tid >> 4, seg = tid & 15;
  float acc = 0.f;
  for (int k = 0; k < 128; ++k) acc += xr[seg * 128 + k] * proj[h * 2048 + seg * 128 + k];
  #pragma unroll
  for (int m = 1; m < 16; m <<= 1) acc += __shfl_xor(acc, m, 64);
  if (seg == 0) out[(long)row * 16 + h] = acc * 0.25f * 0.08838834764831843f;
}

// ---------- indexer scores: sum_h relu(q_h . k) * w_h, f32-accurate ----------
__global__ __launch_bounds__(256) void k_iscore(
    const f16* __restrict__ Ah, const f16* __restrict__ Al,   // idx_q frag layout
    const f16* __restrict__ Bh, const f16* __restrict__ Bl,   // idx_k swizzled
    const float* __restrict__ wts, float* __restrict__ out) {
  const int b = blockIdx.z;
  const int s0 = blockIdx.y * 64, t0 = blockIdx.x * 128;
  if (t0 > s0 + 63) return;
  __shared__ __align__(16) f16 BhS[128 * 128];
  __shared__ __align__(16) f16 BlS[128 * 128];
  const int tid = threadIdx.x;
  const int lane = tid & 63, wid = tid >> 6;
  const int g = lane >> 4, l16 = lane & 15;
  const long brow = ((long)b * 2048 + t0) * 128;
  #pragma unroll
  for (int c = 0; c < 8; ++c) {
    int row = c * 16 + (tid >> 4);
    int col = (tid & 15) * 8;
    glds16(Bh + brow + (long)row * 128 + col, BhS + (size_t)c * 2048 + (size_t)wid * 512);
    glds16(Bl + brow + (long)row * 128 + col, BlS + (size_t)c * 2048 + (size_t)wid * 512);
  }
  __syncthreads();
  const int ws_ = wid >> 1, wt = wid & 1;
  f32x4 sc[2][4];
  #pragma unroll
  for (int m = 0; m < 2; ++m)
    #pragma unroll
    for (int n = 0; n < 4; ++n) sc[m][n] = (f32x4){0.f, 0.f, 0.f, 0.f};
  for (int h = 0; h < 16; ++h) {
    f16x8 ah[2][4], al[2][4];
    #pragma unroll
    for (int m = 0; m < 2; ++m) {
      int rt = (b * 2048 + s0 + ws_ * 32 + m * 16) >> 4;
      #pragma unroll
      for (int kc = 0; kc < 4; ++kc) {
        long o = ((((long)rt * 16 + h) * 4 + kc) * 4 + g) * 128 + l16 * 8;
        ah[m][kc] = *(const f16x8*)(Ah + o);
        al[m][kc] = *(const f16x8*)(Al + o);
      }
    }
    f32x4 l0[2][4], l1[2][4];
    #pragma unroll
    for (int m = 0; m < 2; ++m)
      #pragma unroll
      for (int n = 0; n < 4; ++n) { l0[m][n] = (f32x4){0.f,0.f,0.f,0.f}; l1[m][n] = (f32x4){0.f,0.f,0.f,0.f}; }
    #pragma unroll
    for (int kc = 0; kc < 4; ++kc) {
      #pragma unroll
      for (int n = 0; n < 4; ++n) {
        int row = wt * 64 + n * 16 + l16;
        int ecol = (kc * 32 + g * 8) ^ ((row & 7) * 8);
        f16x8 bh = *(const f16x8*)(BhS + row * 128 + ecol);
        f16x8 bl = *(const f16x8*)(BlS + row * 128 + ecol);
        #pragma unroll
        for (int m = 0; m < 2; ++m) {
          l0[m][n] = __builtin_amdgcn_mfma_f32_16x16x32_f16(ah[m][kc], bh, l0[m][n], 0, 0, 0);
          l1[m][n] = __builtin_amdgcn_mfma_f32_16x16x32_f16(ah[m][kc], bl, l1[m][n], 0, 0, 0);
          l1[m][n] = __builtin_amdgcn_mfma_f32_16x16x32_f16(al[m][kc], bh, l1[m][n], 0, 0, 0);
        }
      }
    }
    #pragma unroll
    for (int m = 0; m < 2; ++m) {
      #pragma unroll
      for (int r = 0; r < 4; ++r) {
        float wv = wts[((long)b * 2048 + s0 + ws_ * 32 + m * 16 + g * 4 + r) * 16 + h];
        #pragma unroll
        for (int n = 0; n < 4; ++n) {
          float lg = l0[m][n][r] + l1[m][n][r] * 4.8828125e-4f;
          if (lg > 0.f) sc[m][n][r] += lg * wv;
        }
      }
    }
  }
  #pragma unroll
  for (int m = 0; m < 2; ++m) {
    #pragma unroll
    for (int n = 0; n < 4; ++n) {
      int tcol = t0 + wt * 64 + n * 16 + l16;
      #pragma unroll
      for (int r = 0; r < 4; ++r) {
        int srow = s0 + ws_ * 32 + m * 16 + g * 4 + r;
        out[((long)b * 2048 + srow) * 2048 + tcol] = sc[m][n][r];
      }
    }
  }
}

// ---------- exact top-512 (causal prefix only), ties -> ascending index ----------
__global__ __launch_bounds__(256) void k_topk(const float* __restrict__ scores, int* __restrict__ sel) {
  const int bs = blockIdx.x;
  const int s = bs & 2047;
  const int n = s + 1;
  const int tid = threadIdx.x;
  int* out = sel + (long)bs * 512;
  if (n <= 512) {
    for (int i = tid; i < 512; i += 256) out[i] = (i < n) ? i : -1;
    return;
  }
  const float* sr = scores + (long)bs * 2048;
  __shared__ u32 hist[256];
  __shared__ u32 sh_prefix;
  __shared__ int sh_R, sh_cnt, sh_tiebase;
  __shared__ int sh_wcnt[4];
  if (tid == 0) { sh_prefix = 0; sh_R = 512; }
  for (int pass = 0; pass < 4; ++pass) {
    int shift = 24 - pass * 8;
    for (int i = tid; i < 256; i += 256) hist[i] = 0;
    __syncthreads();
    u32 pfx = sh_prefix;
    int R = sh_R;
    for (int t = tid; t < n; t += 256) {
      u32 u = __builtin_bit_cast(u32, sr[t]);
      u = (u & 0x80000000u) ? ~u : (u | 0x80000000u);
      bool ok = (pass == 0) || ((u >> (shift + 8)) == (pfx >> (shift + 8)));
      if (ok) atomicAdd(&hist[(u >> shift) & 255], 1u);
    }
    __syncthreads();
    if (tid == 0) {
      int cum = 0, v = 255;
      for (; v >= 0; --v) {
        int c = (int)hist[v];
        if (cum + c >= R) break;
        cum += c;
      }
      sh_prefix = pfx | ((u32)v << shift);
      sh_R = R - cum;
    }
    __syncthreads();
  }
  const u32 thr = sh_prefix;
  const int R = sh_R;
  if (tid == 0) { sh_cnt = 0; sh_tiebase = 0; }
  __syncthreads();
  for (int t = tid; t < n; t += 256) {
    u32 u = __builtin_bit_cast(u32, sr[t]);
    u = (u & 0x80000000u) ? ~u : (u | 0x80000000u);
    if (u > thr) out[atomicAdd(&sh_cnt, 1)] = t;
  }
  __syncthreads();
  const int base = sh_cnt;  // == 512 - R
  for (int c0 = 0; c0 < n; c0 += 256) {
    int t = c0 + tid;
    bool f = false;
    if (t < n) {
      u32 u = __builtin_bit_cast(u32, sr[t]);
      u = (u & 0x80000000u) ? ~u : (u | 0x80000000u);
      f = (u == thr);
    }
    unsigned long long mk = __ballot(f);
    int lane = tid & 63, w = tid >> 6;
    int rank = __popcll(mk & ((1ull << lane) - 1ull));
    if (lane == 0) sh_wcnt[w] = __popcll(mk);
    __syncthreads();
    int wbase = 0;
    for (int i = 0; i < w; ++i) wbase += sh_wcnt[i];
    int tb = sh_tiebase;
    if (f) {
      int pos = tb + wbase + rank;
      if (pos < R) out[base + pos] = t;
    }
    __syncthreads();
    if (tid == 0) sh_tiebase = tb + sh_wcnt[0] + sh_wcnt[1] + sh_wcnt[2] + sh_wcnt[3];
    __syncthreads();
  }
}

// ---------- sparse attention over selected keys ----------
// v3: round-1 structure + per-key XOR swizzle on V columns so the PV scalar
// reads (key = g*8+e) spread across all 32 banks: elem(j,c) stored at
// j*KSTR + (c ^ (((j>>3)&3)<<4)) for c<512; kpe cols (512..575) unswizzled.
#define KSTR 584
__global__ __launch_bounds__(256) void k_attn(
    const int* __restrict__ sel, const u16* __restrict__ qabs, const u16* __restrict__ qpe,
    const u16* __restrict__ kvc, const u16* __restrict__ kpe, u16* __restrict__ oc) {
  const int bs = blockIdx.x;
  const int b = bs >> 11;
  const int tid = threadIdx.x;
  const int lane = tid & 63, wid = tid >> 6;
  const int g = lane >> 4, l16 = lane & 15;
  __shared__ __align__(16) u16 K_lds[32 * KSTR];
  __shared__ float S_lds[2 * 16 * 36];
  __shared__ __align__(16) u16 P_lds[16 * 40];
  __shared__ int t_tile[32];
  __shared__ float m_lds[16], l_lds[16], f_lds[16];
  if (tid < 16) { m_lds[tid] = -3e38f; l_lds[tid] = 0.f; }
  const int half = wid >> 1, jhalf = wid & 1;
  const int kcb = half * 9;
  bf16x8 qf[9];
  #pragma unroll
  for (int i = 0; i < 9; ++i) {
    int kc = kcb + i;
    if (kc < 16) qf[i] = *(const bf16x8*)(qabs + ((long)bs * 16 + l16) * 512 + kc * 32 + g * 8);
    else qf[i] = *(const bf16x8*)(qpe + ((long)bs * 16 + l16) * 64 + (kc - 16) * 32 + g * 8);
  }
  f32x4 oacc[8];
  #pragma unroll
  for (int cf = 0; cf < 8; ++cf) oacc[cf] = (f32x4){0.f, 0.f, 0.f, 0.f};
  __syncthreads();
  for (int jt = 0; jt < 16; ++jt) {
    // gather 32 selected rows (kvc 512 swizzled + kpe 64 plain) into LDS
    #pragma unroll
    for (int it = 0; it < 2; ++it) {
      int cid = it * 256 + tid;
      if (cid < 288) {
        int jr = cid / 9, part = cid % 9;
        int t = sel[(long)bs * 512 + jt * 32 + jr];
        if (part == 0) t_tile[jr] = t;
        int te = t < 0 ? 0 : t;
        const u16* src = (part < 8) ? (kvc + ((long)(b * 2048 + te)) * 512 + part * 64)
                                    : (kpe + ((long)(b * 2048 + te)) * 64);
        const uint4* s4 = (const uint4*)src;
        const int swz = ((jr >> 3) & 3) << 4;
        if (part < 8) {
          #pragma unroll
          for (int i = 0; i < 8; ++i) {
            int cs = (part * 64 + i * 8) ^ swz;
            *(uint4*)&K_lds[jr * KSTR + cs] = s4[i];
          }
        } else {
          #pragma unroll
          for (int i = 0; i < 8; ++i)
            *(uint4*)&K_lds[jr * KSTR + 512 + i * 8] = s4[i];
        }
      }
    }
    __syncthreads();
    // QK^T (each wave: 16 j of this tile's 32, half of K)
    const int key = jhalf * 16 + l16;
    const int kswz = ((key >> 3) & 3) << 4;
    f32x4 sacc = (f32x4){0.f, 0.f, 0.f, 0.f};
    #pragma unroll
    for (int i = 0; i < 9; ++i) {
      int kc = kcb + i;
      bf16x8 bfr;
      if (kc < 16) {
        int cs = (kc * 32 + g * 8) ^ kswz;
        bfr = *(const bf16x8*)&K_lds[key * KSTR + cs];
      } else {
        bfr = *(const bf16x8*)&K_lds[key * KSTR + kc * 32 + g * 8];
      }
      sacc = __builtin_amdgcn_mfma_f32_16x16x32_bf16(qf[i], bfr, sacc, 0, 0, 0);
    }
    int tj = t_tile[key];
    #pragma unroll
    for (int r = 0; r < 4; ++r) {
      int h = g * 4 + r;
      S_lds[half * 576 + h * 36 + key] = (tj < 0) ? -1e30f : sacc[r] * 0.07216878364870322f;
    }
    __syncthreads();
    // online softmax update
    {
      int h = tid >> 4, q16 = tid & 15;
      float vs[2];
      float mx = -3e38f;
      #pragma unroll
      for (int k = 0; k < 2; ++k) {
        int j = q16 + k * 16;
        vs[k] = S_lds[h * 36 + j] + S_lds[576 + h * 36 + j];
        mx = fmaxf(mx, vs[k]);
      }
      #pragma unroll
      for (int m = 1; m < 16; m <<= 1) mx = fmaxf(mx, __shfl_xor(mx, m, 64));
      float m_old = m_lds[h];
      float m_new = fmaxf(m_old, mx);
      float ps = 0.f;
      #pragma unroll
      for (int k = 0; k < 2; ++k) {
        float p = __expf(vs[k] - m_new);
        ps += p;
        P_lds[h * 40 + q16 + k * 16] = f2bf(p);
      }
      #pragma unroll
      for (int m = 1; m < 16; m <<= 1) ps += __shfl_xor(ps, m, 64);
      if (q16 == 0) {
        float f = __expf(m_old - m_new);
        f_lds[h] = f;
        m_lds[h] = m_new;
        l_lds[h] = l_lds[h] * f + ps;
      }
    }
    __syncthreads();
    // rescale + PV (scalar V^T reads, conflict-free via swizzle)
    float fr[4];
    #pragma unroll
    for (int r = 0; r < 4; ++r) fr[r] = f_lds[g * 4 + r];
    #pragma unroll
    for (int cf = 0; cf < 8; ++cf)
      #pragma unroll
      for (int r = 0; r < 4; ++r) oacc[cf][r] *= fr[r];
    bf16x8 pa = *(const bf16x8*)&P_lds[l16 * 40 + g * 8];
    #pragma unroll
    for (int cf = 0; cf < 8; ++cf) {
      int colv = (wid * 128 + cf * 16 + l16) ^ (g << 4);
      bf16x8 vb;
      #pragma unroll
      for (int e = 0; e < 8; ++e) vb[e] = (short)K_lds[(g * 8 + e) * KSTR + colv];
      oacc[cf] = __builtin_amdgcn_mfma_f32_16x16x32_bf16(pa, vb, oacc[cf], 0, 0, 0);
    }
    __syncthreads();
  }
  float li[4];
  #pragma unroll
  for (int r = 0; r < 4; ++r) li[r] = 1.0f / l_lds[g * 4 + r];
  #pragma unroll
  for (int cf = 0; cf < 8; ++cf) {
    int col = wid * 128 + cf * 16 + l16;
    #pragma unroll
    for (int r = 0; r < 4; ++r) {
      int h = g * 4 + r;
      oc[((long)bs * 16 + h) * 512 + col] = f2bf(oacc[cf][r] * li[r]);
    }
  }
}

// ---------- launcher ----------
extern "C" void kernel_launch(void* const* d_in, const int* in_sizes, int n_in,
                              void* d_out, int out_size, void* d_ws, size_t ws_size,
                              hipStream_t stream) {
  const float* x = (const float*)d_in[0];
  const float* fcos = (const float*)d_in[1];
  const float* fsin = (const float*)d_in[2];
  const float* wq_a = (const float*)d_in[4];
  const float* q_norm_w = (const float*)d_in[5];
  const float* wq_b = (const float*)d_in[6];
  const float* wkv_a = (const float*)d_in[7];
  const float* kv_norm_w = (const float*)d_in[8];
  const float* wkv_b = (const float*)d_in[9];
  const float* wo = (const float*)d_in[10];
  const float* idx_wq_b = (const float*)d_in[11];
  const float* idx_wk = (const float*)d_in[12];
  const float* iknw = (const float*)d_in[13];
  const float* iknb = (const float*)d_in[14];
  const float* iwp = (const float*)d_in[15];

  size_t off = 0;
  char* wsb = (char*)d_ws;
  auto alloc = [&](size_t bytes) -> char* {
    char* p = wsb + off;
    off += (bytes + 255) & ~(size_t)255;
    return p;
  };
  u16* x_b16  = (u16*)alloc(16777216);
  f16* xh     = (f16*)alloc(16777216);
  f16* xl     = (f16*)alloc(16777216);
  f16* wqa_h  = (f16*)alloc(3145728);
  f16* wqa_l  = (f16*)alloc(3145728);
  float* qr   = (float*)alloc(12582912);
  f16* qr_h   = (f16*)alloc(6291456);
  f16* qr_l   = (f16*)alloc(6291456);
  u16* qr_b   = (u16*)alloc(6291456);
  u16* wqb_b  = (u16*)alloc(4718592);
  char* QBIG  = alloc(50331648);          // q f32 -> idxq f32 -> scores f32 -> o_c bf16
  u16* qn_b   = (u16*)alloc(16777216);
  u16* qpe_b  = (u16*)alloc(8388608);
  u16* wkva_b = (u16*)alloc(2359296);
  float* kvraw= (float*)alloc(9437184);
  u16* kvc_b  = (u16*)alloc(4194304);
  u16* kpe_b  = (u16*)alloc(524288);
  u16* wkvb_b = (u16*)alloc(4194304);
  u16* wkvbnt = (u16*)alloc(2097152);
  u16* wo_b   = (u16*)alloc(8388608);
  f16* iwqb_h = (f16*)alloc(3145728);
  f16* iwqb_l = (f16*)alloc(3145728);
  f16* idxq_h = (f16*)alloc(16777216);
  f16* idxq_l = (f16*)alloc(16777216);
  f16* iwk_h  = (f16*)alloc(524288);
  f16* iwk_l  = (f16*)alloc(524288);
  float* idxk_f = (float*)alloc(2097152);
  f16* idxk_h = (f16*)alloc(1048576);
  f16* idxk_l = (f16*)alloc(1048576);
  float* idxw = (float*)alloc(262144);
  int* sel    = (int*)alloc(8388608);
  // aliases (lifetime-disjoint)
  u16* q_abs  = (u16*)xh;                 // xh+xl region, used after last xh/xl read
  float* q_f32 = (float*)QBIG;
  float* idxq_f32 = (float*)QBIG;
  float* scores = (float*)QBIG;
  u16* o_c    = (u16*)QBIG;
  u16* o_d    = (u16*)idxq_h;

  // 1. conversions / splits
  k_cvt_split_x<<<8192, 256, 0, stream>>>(x, x_b16, xh, xl, 8388608L);
  k_split<<<1536, 256, 0, stream>>>(wq_a, wqa_h, wqa_l, 1572864L);
  k_cvt_bf16<<<2304, 256, 0, stream>>>(wq_b, wqb_b, 2359296L);
  k_cvt_bf16<<<1152, 256, 0, stream>>>(wkv_a, wkva_b, 1179648L);
  k_cvt_wkvb<<<8192, 256, 0, stream>>>(wkv_b, wkvb_b, wkvbnt);
  k_cvt_bf16<<<4096, 256, 0, stream>>>(wo, wo_b, 4194304L);
  k_split<<<1536, 256, 0, stream>>>(idx_wq_b, iwqb_h, iwqb_l, 1572864L);
  k_split<<<256, 256, 0, stream>>>(idx_wk, iwk_h, iwk_l, 262144L);

  // 2. qr = rmsnorm(x @ wq_a.T)  [f32-accurate]
  k_gemm_f16pair<<<dim3(6, 32, 1), 256, 0, stream>>>(xh, xl, wqa_h, wqa_l, qr, 768, 2048, 2048, 2048, 768);
  k_rms_qr<<<4096, 256, 0, stream>>>(qr, q_norm_w, qr_h, qr_l, qr_b);

  // 3. q = qr @ wq_b.T  (bf16 ok) ; rope/split
  k_gemm_bt<<<dim3(24, 32, 1), 256, 0, stream>>>(qr_b, wqb_b, QBIG, 3072, 768, 768, 768, 3072, 0, 0, 0, 0);
  k_qpost<<<4096, 256, 0, stream>>>(q_f32, fcos, fsin, qn_b, qpe_b);

  // 4. kv = x @ wkv_a.T ; rms + rope
  k_gemm_bt<<<dim3(5, 32, 1), 256, 0, stream>>>(x_b16, wkva_b, kvraw, 576, 2048, 2048, 2048, 576, 0, 0, 0, 0);
  k_kvpost<<<4096, 256, 0, stream>>>(kvraw, kv_norm_w, fcos, fsin, kvc_b, kpe_b);

  // 5. indexer q/k/w  [f32-accurate]
  k_gemm_f16pair<<<dim3(16, 32, 1), 256, 0, stream>>>(qr_h, qr_l, iwqb_h, iwqb_l, idxq_f32, 2048, 768, 768, 768, 2048);
  k_idxqpost<<<4096, 256, 0, stream>>>(idxq_f32, fcos, fsin, idxq_h, idxq_l);
  k_gemm_f16pair<<<dim3(1, 32, 1), 256, 0, stream>>>(xh, xl, iwk_h, iwk_l, idxk_f, 128, 2048, 2048, 2048, 128);
  k_idxkpost<<<4096, 128, 0, stream>>>(idxk_f, iknw, iknb, fcos, fsin, idxk_h, idxk_l);
  k_wproj<<<4096, 256, 0, stream>>>(x, iwp, idxw);

  // 6. q_abs per head (after last use of xh/xl; writes over them)
  k_gemm_bt<<<dim3(4, 32, 16), 256, 0, stream>>>(qn_b, wkvbnt, q_abs, 512, 128, 2048, 128, 8192, 128, 65536, 512, 1);

  // 7. indexer scores (causal tiles) + exact top-512
  k_iscore<<<dim3(16, 32, 2), 256, 0, stream>>>(idxq_h, idxq_l, idxk_h, idxk_l, idxw, scores);
  k_topk<<<4096, 256, 0, stream>>>(scores, sel);

  // 8. sparse attention -> o_c  (overwrites scores region)
  k_attn<<<4096, 256, 0, stream>>>(sel, q_abs, qpe_b, kvc_b, kpe_b, o_c);

  // 9. o_d = per-head o_c @ wkv_b3[:,128:,:]  then  out = o_d @ wo.T
  k_gemm_bt<<<dim3(1, 32, 16), 256, 0, stream>>>(o_c, wkvb_b + 65536, o_d, 128, 512, 8192, 512, 2048, 512, 131072, 128, 1);
  k_gemm_bt<<<dim3(16, 32, 1), 256, 0, stream>>>(o_d, wo_b, d_out, 2048, 2048, 2048, 2048, 2048, 0, 0, 0, 0);
}

// Round 4
// 1295.780 us; speedup vs baseline: 1.1914x; 1.1823x over previous
//
#include <hip/hip_runtime.h>

typedef short bf16x8 __attribute__((ext_vector_type(8)));
typedef short s16x4 __attribute__((ext_vector_type(4)));
typedef _Float16 f16x8 __attribute__((ext_vector_type(8)));
typedef float f32x4 __attribute__((ext_vector_type(4)));
typedef _Float16 f16;
typedef unsigned short u16;
typedef unsigned int u32;

#define DEVFN static __device__ __forceinline__

// ---------- helpers ----------
DEVFN u16 f2bf(float f) {
  u32 u = __builtin_bit_cast(u32, f);
  return (u16)((u + 0x7FFFu + ((u >> 16) & 1u)) >> 16);
}

DEVFN void glds16(const void* g, void* l) {
  __builtin_amdgcn_global_load_lds((const __attribute__((address_space(1))) void*)g,
                                   (__attribute__((address_space(3))) void*)l, 16, 0, 0);
}

DEVFN u32 lds_u32(const void* p) {
  return (u32)(size_t)(const __attribute__((address_space(3))) void*)p;
}

DEVFN s16x4 ds_tr16(u32 addr) {
  s16x4 d;
  asm volatile("ds_read_b64_tr_b16 %0, %1" : "=v"(d) : "v"(addr));
  return d;
}

DEVFN bf16x8 combine8(s16x4 a, s16x4 b) {
  union { s16x4 h[2]; bf16x8 v; } u;
  u.h[0] = a; u.h[1] = b;
  return u.v;
}

DEVFN void wsplit(f16* oh, f16* ol, long o, float v) {
  f16 hh = (f16)v;
  oh[o] = hh;
  ol[o] = (f16)((v - (float)hh) * 2048.0f);
}

// idx_q fragment-friendly layout: [row/16][h][kc][g][ri][8]
DEVFN long idxq_off(int row, int h, int c) {
  return ((((long)(row >> 4) * 16 + h) * 4 + (c >> 5)) * 4 + ((c >> 3) & 3)) * 128
         + (long)(row & 15) * 8 + (c & 7);
}

// ---------- elementwise conversions ----------
__global__ __launch_bounds__(256) void k_cvt_bf16(const float* __restrict__ in, u16* __restrict__ out, long n) {
  long i = ((long)blockIdx.x * 256 + threadIdx.x) * 4;
  if (i < n) {
    float4 v = *(const float4*)(in + i);
    out[i] = f2bf(v.x); out[i + 1] = f2bf(v.y); out[i + 2] = f2bf(v.z); out[i + 3] = f2bf(v.w);
  }
}

__global__ __launch_bounds__(256) void k_split(const float* __restrict__ in, f16* __restrict__ oh, f16* __restrict__ ol, long n) {
  long i = ((long)blockIdx.x * 256 + threadIdx.x) * 4;
  if (i < n) {
    float4 v = *(const float4*)(in + i);
    float a[4] = {v.x, v.y, v.z, v.w};
    #pragma unroll
    for (int k = 0; k < 4; ++k) {
      f16 hh = (f16)a[k];
      oh[i + k] = hh;
      ol[i + k] = (f16)((a[k] - (float)hh) * 2048.0f);
    }
  }
}

// fused: x -> bf16 copy + f16 split (single read of x)
__global__ __launch_bounds__(256) void k_cvt_split_x(const float* __restrict__ in, u16* __restrict__ ob,
    f16* __restrict__ oh, f16* __restrict__ ol, long n) {
  long i = ((long)blockIdx.x * 256 + threadIdx.x) * 4;
  if (i < n) {
    float4 v = *(const float4*)(in + i);
    float a[4] = {v.x, v.y, v.z, v.w};
    #pragma unroll
    for (int k = 0; k < 4; ++k) {
      ob[i + k] = f2bf(a[k]);
      f16 hh = (f16)a[k];
      oh[i + k] = hh;
      ol[i + k] = (f16)((a[k] - (float)hh) * 2048.0f);
    }
  }
}

// wkv_b -> full bf16 copy + transposed nope part [h][c][d]
__global__ __launch_bounds__(256) void k_cvt_wkvb(const float* __restrict__ wkvb, u16* __restrict__ full_b, u16* __restrict__ nope_t) {
  long i = (long)blockIdx.x * 256 + threadIdx.x;
  if (i >= 2097152) return;
  float v = wkvb[i];
  u16 bv = f2bf(v);
  full_b[i] = bv;
  long row = i >> 9;
  int c = (int)(i & 511);
  int h = (int)(row >> 8);
  int d = (int)(row & 255);
  if (d < 128) nope_t[(long)h * 65536 + (long)c * 128 + d] = bv;
}

// ---------- generic C = A * B^T, bf16 MFMA, 128x128 tile ----------
__global__ __launch_bounds__(256) void k_gemm_bt(
    const u16* __restrict__ A, const u16* __restrict__ B, void* __restrict__ Cout,
    int N, int K, long lda, long ldb, long ldc, long sA, long sB, long sC, int outBf16) {
  A += (long)blockIdx.z * sA;
  B += (long)blockIdx.z * sB;
  const long m0 = (long)blockIdx.y * 128;
  const long n0 = (long)blockIdx.x * 128;
  __shared__ __align__(16) u16 As[128 * 32];
  __shared__ __align__(16) u16 Bs[128 * 32];
  const int tid = threadIdx.x;
  const int lane = tid & 63, wid = tid >> 6;
  const int g = lane >> 4, l16 = lane & 15;
  const int srow = tid >> 2;
  const int scol = (tid & 3) * 8;
  const int wm = wid >> 1, wn = wid & 1;
  f32x4 acc[4][4];
  #pragma unroll
  for (int m = 0; m < 4; ++m)
    #pragma unroll
    for (int n = 0; n < 4; ++n) acc[m][n] = (f32x4){0.f, 0.f, 0.f, 0.f};
  for (int k0 = 0; k0 < K; k0 += 32) {
    long rb0 = n0 + srow; if (rb0 >= N) rb0 = 0;
    long rb1 = n0 + 64 + srow; if (rb1 >= N) rb1 = 0;
    glds16(A + (m0 + srow) * lda + k0 + scol, As + (size_t)wid * 512);
    glds16(A + (m0 + 64 + srow) * lda + k0 + scol, As + 2048 + (size_t)wid * 512);
    glds16(B + rb0 * ldb + k0 + scol, Bs + (size_t)wid * 512);
    glds16(B + rb1 * ldb + k0 + scol, Bs + 2048 + (size_t)wid * 512);
    __syncthreads();
    bf16x8 af[4], bfv[4];
    #pragma unroll
    for (int m = 0; m < 4; ++m) af[m] = *(const bf16x8*)(As + (wm * 64 + m * 16 + l16) * 32 + g * 8);
    #pragma unroll
    for (int n = 0; n < 4; ++n) bfv[n] = *(const bf16x8*)(Bs + (wn * 64 + n * 16 + l16) * 32 + g * 8);
    #pragma unroll
    for (int m = 0; m < 4; ++m)
      #pragma unroll
      for (int n = 0; n < 4; ++n)
        acc[m][n] = __builtin_amdgcn_mfma_f32_16x16x32_bf16(af[m], bfv[n], acc[m][n], 0, 0, 0);
    __syncthreads();
  }
  const long cz = (long)blockIdx.z * sC;
  if (outBf16) {
    u16* C = (u16*)Cout;
    #pragma unroll
    for (int m = 0; m < 4; ++m) {
      const long row = m0 + wm * 64 + m * 16 + g * 4;
      #pragma unroll
      for (int n = 0; n < 4; ++n) {
        const long col = n0 + wn * 64 + n * 16 + l16;
        if (col < N) {
          #pragma unroll
          for (int r = 0; r < 4; ++r) C[cz + (row + r) * ldc + col] = f2bf(acc[m][n][r]);
        }
      }
    }
  } else {
    float* C = (float*)Cout;
    #pragma unroll
    for (int m = 0; m < 4; ++m) {
      const long row = m0 + wm * 64 + m * 16 + g * 4;
      #pragma unroll
      for (int n = 0; n < 4; ++n) {
        const long col = n0 + wn * 64 + n * 16 + l16;
        if (col < N) {
          #pragma unroll
          for (int r = 0; r < 4; ++r) C[cz + (row + r) * ldc + col] = acc[m][n][r];
        }
      }
    }
  }
}

// ---------- f32-accurate C = A * B^T via f16 pair split (3 MFMA / tile) ----------
__global__ __launch_bounds__(256) void k_gemm_f16pair(
    const f16* __restrict__ Ah, const f16* __restrict__ Al,
    const f16* __restrict__ Bh, const f16* __restrict__ Bl,
    float* __restrict__ C, int N, int K, long lda, long ldb, long ldc) {
  const long m0 = (long)blockIdx.y * 128;
  const long n0 = (long)blockIdx.x * 128;
  __shared__ __align__(16) f16 AhS[4096], AlS[4096], BhS[4096], BlS[4096];
  const int tid = threadIdx.x;
  const int lane = tid & 63, wid = tid >> 6;
  const int g = lane >> 4, l16 = lane & 15;
  const int srow = tid >> 2;
  const int scol = (tid & 3) * 8;
  const int wm = wid >> 1, wn = wid & 1;
  f32x4 a0[4][4], a1[4][4];
  #pragma unroll
  for (int m = 0; m < 4; ++m)
    #pragma unroll
    for (int n = 0; n < 4; ++n) { a0[m][n] = (f32x4){0.f,0.f,0.f,0.f}; a1[m][n] = (f32x4){0.f,0.f,0.f,0.f}; }
  for (int k0 = 0; k0 < K; k0 += 32) {
    long rb0 = n0 + srow; if (rb0 >= N) rb0 = 0;
    long rb1 = n0 + 64 + srow; if (rb1 >= N) rb1 = 0;
    glds16(Ah + (m0 + srow) * lda + k0 + scol, AhS + (size_t)wid * 512);
    glds16(Ah + (m0 + 64 + srow) * lda + k0 + scol, AhS + 2048 + (size_t)wid * 512);
    glds16(Al + (m0 + srow) * lda + k0 + scol, AlS + (size_t)wid * 512);
    glds16(Al + (m0 + 64 + srow) * lda + k0 + scol, AlS + 2048 + (size_t)wid * 512);
    glds16(Bh + rb0 * ldb + k0 + scol, BhS + (size_t)wid * 512);
    glds16(Bh + rb1 * ldb + k0 + scol, BhS + 2048 + (size_t)wid * 512);
    glds16(Bl + rb0 * ldb + k0 + scol, BlS + (size_t)wid * 512);
    glds16(Bl + rb1 * ldb + k0 + scol, BlS + 2048 + (size_t)wid * 512);
    __syncthreads();
    f16x8 ah[4], al[4];
    #pragma unroll
    for (int m = 0; m < 4; ++m) {
      ah[m] = *(const f16x8*)(AhS + (wm * 64 + m * 16 + l16) * 32 + g * 8);
      al[m] = *(const f16x8*)(AlS + (wm * 64 + m * 16 + l16) * 32 + g * 8);
    }
    #pragma unroll
    for (int n = 0; n < 4; ++n) {
      f16x8 bh = *(const f16x8*)(BhS + (wn * 64 + n * 16 + l16) * 32 + g * 8);
      f16x8 bl = *(const f16x8*)(BlS + (wn * 64 + n * 16 + l16) * 32 + g * 8);
      #pragma unroll
      for (int m = 0; m < 4; ++m) {
        a0[m][n] = __builtin_amdgcn_mfma_f32_16x16x32_f16(ah[m], bh, a0[m][n], 0, 0, 0);
        a1[m][n] = __builtin_amdgcn_mfma_f32_16x16x32_f16(ah[m], bl, a1[m][n], 0, 0, 0);
        a1[m][n] = __builtin_amdgcn_mfma_f32_16x16x32_f16(al[m], bh, a1[m][n], 0, 0, 0);
      }
    }
    __syncthreads();
  }
  #pragma unroll
  for (int m = 0; m < 4; ++m) {
    const long row = m0 + wm * 64 + m * 16 + g * 4;
    #pragma unroll
    for (int n = 0; n < 4; ++n) {
      const long col = n0 + wn * 64 + n * 16 + l16;
      if (col < N) {
        #pragma unroll
        for (int r = 0; r < 4; ++r)
          C[(row + r) * ldc + col] = a0[m][n][r] + a1[m][n][r] * 4.8828125e-4f;
      }
    }
  }
}

// ---------- per-row post kernels ----------
__global__ __launch_bounds__(256) void k_rms_qr(float* __restrict__ qr, const float* __restrict__ w,
    f16* __restrict__ qh, f16* __restrict__ ql, u16* __restrict__ qb) {
  const int row = blockIdx.x, tid = threadIdx.x;
  float v[3];
  float ss = 0.f;
  #pragma unroll
  for (int i = 0; i < 3; ++i) { v[i] = qr[(long)row * 768 + tid + i * 256]; ss += v[i] * v[i]; }
  #pragma unroll
  for (int m = 1; m < 64; m <<= 1) ss += __shfl_xor(ss, m, 64);
  __shared__ float wsum[4];
  if ((tid & 63) == 0) wsum[tid >> 6] = ss;
  __syncthreads();
  float tot = wsum[0] + wsum[1] + wsum[2] + wsum[3];
  float gsc = 1.0f / sqrtf(tot * (1.0f / 768.0f) + 1e-6f);
  #pragma unroll
  for (int i = 0; i < 3; ++i) {
    long o = (long)row * 768 + tid + i * 256;
    float y = v[i] * gsc * w[tid + i * 256];
    qr[o] = y;
    f16 hh = (f16)y;
    qh[o] = hh;
    ql[o] = (f16)((y - (float)hh) * 2048.0f);
    qb[o] = f2bf(y);
  }
}

__global__ __launch_bounds__(256) void k_kvpost(const float* __restrict__ kvraw, const float* __restrict__ w,
    const float* __restrict__ cosb, const float* __restrict__ sinb,
    u16* __restrict__ kvc, u16* __restrict__ kpe) {
  const int row = blockIdx.x, tid = threadIdx.x;
  const int s = row & 2047;
  float v0 = kvraw[(long)row * 576 + tid];
  float v1 = kvraw[(long)row * 576 + 256 + tid];
  float ss = v0 * v0 + v1 * v1;
  #pragma unroll
  for (int m = 1; m < 64; m <<= 1) ss += __shfl_xor(ss, m, 64);
  __shared__ float wsum[4];
  if ((tid & 63) == 0) wsum[tid >> 6] = ss;
  __syncthreads();
  float tot = wsum[0] + wsum[1] + wsum[2] + wsum[3];
  float gsc = 1.0f / sqrtf(tot * (1.0f / 512.0f) + 1e-6f);
  kvc[(long)row * 512 + tid] = f2bf(v0 * gsc * w[tid]);
  kvc[(long)row * 512 + 256 + tid] = f2bf(v1 * gsc * w[256 + tid]);
  if (tid < 32) {
    float x1 = kvraw[(long)row * 576 + 512 + tid];
    float x2 = kvraw[(long)row * 576 + 544 + tid];
    float c = cosb[s * 32 + tid], sn = sinb[s * 32 + tid];
    kpe[(long)row * 64 + tid] = f2bf(x1 * c - x2 * sn);
    kpe[(long)row * 64 + 32 + tid] = f2bf(x1 * sn + x2 * c);
  }
}

__global__ __launch_bounds__(256) void k_qpost(const float* __restrict__ q,
    const float* __restrict__ cosb, const float* __restrict__ sinb,
    u16* __restrict__ qn, u16* __restrict__ qpe) {
  const int row = blockIdx.x, tid = threadIdx.x;
  const int s = row & 2047;
  const long qb = (long)row * 3072;
  #pragma unroll
  for (int i = 0; i < 8; ++i) {
    int idx = tid + i * 256;
    int h = idx >> 7, d = idx & 127;
    qn[(long)row * 2048 + idx] = f2bf(q[qb + h * 192 + d]);
  }
  #pragma unroll
  for (int i = 0; i < 2; ++i) {
    int p = tid + i * 256;
    int h = p >> 5, e = p & 31;
    float x1 = q[qb + h * 192 + 128 + e];
    float x2 = q[qb + h * 192 + 160 + e];
    float c = cosb[s * 32 + e], sn = sinb[s * 32 + e];
    qpe[(long)row * 1024 + h * 64 + e] = f2bf(x1 * c - x2 * sn);
    qpe[(long)row * 1024 + h * 64 + 32 + e] = f2bf(x1 * sn + x2 * c);
  }
}

__global__ __launch_bounds__(256) void k_idxqpost(const float* __restrict__ iq,
    const float* __restrict__ cosb, const float* __restrict__ sinb,
    f16* __restrict__ oh, f16* __restrict__ ol) {
  const int row = blockIdx.x, tid = threadIdx.x;
  const int s = row & 2047;
  const long ib = (long)row * 2048;
  #pragma unroll
  for (int i = 0; i < 2; ++i) {
    int p = tid + i * 256;
    int h = p >> 5, e = p & 31;
    float x1 = iq[ib + h * 128 + e], x2 = iq[ib + h * 128 + 32 + e];
    float c = cosb[s * 32 + e], sn = sinb[s * 32 + e];
    wsplit(oh, ol, idxq_off(row, h, e), x1 * c - x2 * sn);
    wsplit(oh, ol, idxq_off(row, h, e + 32), x1 * sn + x2 * c);
  }
  #pragma unroll
  for (int i = 0; i < 4; ++i) {
    int idx = tid + i * 256;
    int h = idx >> 6, e2 = idx & 63;
    int c = 64 + e2;
    wsplit(oh, ol, idxq_off(row, h, c), iq[ib + h * 128 + c]);
  }
}

__global__ __launch_bounds__(128) void k_idxkpost(const float* __restrict__ ik,
    const float* __restrict__ w, const float* __restrict__ bb,
    const float* __restrict__ cosb, const float* __restrict__ sinb,
    f16* __restrict__ oh, f16* __restrict__ ol) {
  const int row = blockIdx.x, tid = threadIdx.x;
  const int s = row & 2047;
  float v = ik[(long)row * 128 + tid];
  float sum = v;
  #pragma unroll
  for (int m = 1; m < 64; m <<= 1) sum += __shfl_xor(sum, m, 64);
  __shared__ float r0[2], r1[2];
  __shared__ float ybuf[128];
  if ((tid & 63) == 0) r0[tid >> 6] = sum;
  __syncthreads();
  float mean = (r0[0] + r0[1]) * (1.0f / 128.0f);
  float d = v - mean;
  float s2 = d * d;
  #pragma unroll
  for (int m = 1; m < 64; m <<= 1) s2 += __shfl_xor(s2, m, 64);
  if ((tid & 63) == 0) r1[tid >> 6] = s2;
  __syncthreads();
  float var = (r1[0] + r1[1]) * (1.0f / 128.0f);
  float y = d * (1.0f / sqrtf(var + 1e-6f)) * w[tid] + bb[tid];
  ybuf[tid] = y;
  __syncthreads();
  float outv = y;
  if (tid < 64) {
    int e = tid & 31;
    float x1 = ybuf[e], x2 = ybuf[32 + e];
    float c = cosb[s * 32 + e], sn = sinb[s * 32 + e];
    outv = (tid < 32) ? (x1 * c - x2 * sn) : (x1 * sn + x2 * c);
  }
  int csw = tid ^ ((row & 7) << 3);  // pre-swizzled for conflict-free LDS reads in k_iscore
  long o = (long)row * 128 + csw;
  f16 hh = (f16)outv;
  oh[o] = hh;
  ol[o] = (f16)((outv - (float)hh) * 2048.0f);
}

// idx weights projection (N=16), f32 exact
__global__ __launch_bounds__(256) void k_wproj(const float* __restrict__ x,
    const float* __restrict__ proj, float* __restrict__ out) {
  const int row = blockIdx.x, tid = threadIdx.x;
  __shared__ float xr[2048];
  #pragma unroll
  for (int i = 0; i < 8; ++i) xr[tid + i * 256] = x[(long)row * 2048 + tid + i * 256];
  __syncthreads();
  int h = tid >> 4, seg = tid & 15;
  float acc = 0.f;
  for (int k = 0; k < 128; ++k) acc += xr[seg * 128 + k] * proj[h * 2048 + seg * 128 + k];
  #pragma unroll
  for (int m = 1; m < 16; m <<= 1) acc += __shfl_xor(acc, m, 64);
  if (seg == 0) out[(long)row * 16 + h] = acc * 0.25f * 0.08838834764831843f;
}

// ---------- indexer scores: sum_h relu(q_h . k) * w_h, f32-accurate ----------
__global__ __launch_bounds__(256) void k_iscore(
    const f16* __restrict__ Ah, const f16* __restrict__ Al,   // idx_q frag layout
    const f16* __restrict__ Bh, const f16* __restrict__ Bl,   // idx_k swizzled
    const float* __restrict__ wts, float* __restrict__ out) {
  const int b = blockIdx.z;
  const int s0 = blockIdx.y * 64, t0 = blockIdx.x * 128;
  if (t0 > s0 + 63) return;
  __shared__ __align__(16) f16 BhS[128 * 128];
  __shared__ __align__(16) f16 BlS[128 * 128];
  const int tid = threadIdx.x;
  const int lane = tid & 63, wid = tid >> 6;
  const int g = lane >> 4, l16 = lane & 15;
  const long brow = ((long)b * 2048 + t0) * 128;
  #pragma unroll
  for (int c = 0; c < 8; ++c) {
    int row = c * 16 + (tid >> 4);
    int col = (tid & 15) * 8;
    glds16(Bh + brow + (long)row * 128 + col, BhS + (size_t)c * 2048 + (size_t)wid * 512);
    glds16(Bl + brow + (long)row * 128 + col, BlS + (size_t)c * 2048 + (size_t)wid * 512);
  }
  __syncthreads();
  const int ws_ = wid >> 1, wt = wid & 1;
  f32x4 sc[2][4];
  #pragma unroll
  for (int m = 0; m < 2; ++m)
    #pragma unroll
    for (int n = 0; n < 4; ++n) sc[m][n] = (f32x4){0.f, 0.f, 0.f, 0.f};
  for (int h = 0; h < 16; ++h) {
    f16x8 ah[2][4], al[2][4];
    #pragma unroll
    for (int m = 0; m < 2; ++m) {
      int rt = (b * 2048 + s0 + ws_ * 32 + m * 16) >> 4;
      #pragma unroll
      for (int kc = 0; kc < 4; ++kc) {
        long o = ((((long)rt * 16 + h) * 4 + kc) * 4 + g) * 128 + l16 * 8;
        ah[m][kc] = *(const f16x8*)(Ah + o);
        al[m][kc] = *(const f16x8*)(Al + o);
      }
    }
    f32x4 l0[2][4], l1[2][4];
    #pragma unroll
    for (int m = 0; m < 2; ++m)
      #pragma unroll
      for (int n = 0; n < 4; ++n) { l0[m][n] = (f32x4){0.f,0.f,0.f,0.f}; l1[m][n] = (f32x4){0.f,0.f,0.f,0.f}; }
    #pragma unroll
    for (int kc = 0; kc < 4; ++kc) {
      #pragma unroll
      for (int n = 0; n < 4; ++n) {
        int row = wt * 64 + n * 16 + l16;
        int ecol = (kc * 32 + g * 8) ^ ((row & 7) * 8);
        f16x8 bh = *(const f16x8*)(BhS + row * 128 + ecol);
        f16x8 bl = *(const f16x8*)(BlS + row * 128 + ecol);
        #pragma unroll
        for (int m = 0; m < 2; ++m) {
          l0[m][n] = __builtin_amdgcn_mfma_f32_16x16x32_f16(ah[m][kc], bh, l0[m][n], 0, 0, 0);
          l1[m][n] = __builtin_amdgcn_mfma_f32_16x16x32_f16(ah[m][kc], bl, l1[m][n], 0, 0, 0);
          l1[m][n] = __builtin_amdgcn_mfma_f32_16x16x32_f16(al[m][kc], bh, l1[m][n], 0, 0, 0);
        }
      }
    }
    #pragma unroll
    for (int m = 0; m < 2; ++m) {
      #pragma unroll
      for (int r = 0; r < 4; ++r) {
        float wv = wts[((long)b * 2048 + s0 + ws_ * 32 + m * 16 + g * 4 + r) * 16 + h];
        #pragma unroll
        for (int n = 0; n < 4; ++n) {
          float lg = l0[m][n][r] + l1[m][n][r] * 4.8828125e-4f;
          if (lg > 0.f) sc[m][n][r] += lg * wv;
        }
      }
    }
  }
  #pragma unroll
  for (int m = 0; m < 2; ++m) {
    #pragma unroll
    for (int n = 0; n < 4; ++n) {
      int tcol = t0 + wt * 64 + n * 16 + l16;
      #pragma unroll
      for (int r = 0; r < 4; ++r) {
        int srow = s0 + ws_ * 32 + m * 16 + g * 4 + r;
        out[((long)b * 2048 + srow) * 2048 + tcol] = sc[m][n][r];
      }
    }
  }
}

// ---------- exact top-512 (causal prefix only), ties -> ascending index ----------
__global__ __launch_bounds__(256) void k_topk(const float* __restrict__ scores, int* __restrict__ sel) {
  const int bs = blockIdx.x;
  const int s = bs & 2047;
  const int n = s + 1;
  const int tid = threadIdx.x;
  int* out = sel + (long)bs * 512;
  if (n <= 512) {
    for (int i = tid; i < 512; i += 256) out[i] = (i < n) ? i : -1;
    return;
  }
  const float* sr = scores + (long)bs * 2048;
  __shared__ u32 hist[256];
  __shared__ u32 sh_prefix;
  __shared__ int sh_R, sh_cnt, sh_tiebase;
  __shared__ int sh_wcnt[4];
  if (tid == 0) { sh_prefix = 0; sh_R = 512; }
  for (int pass = 0; pass < 4; ++pass) {
    int shift = 24 - pass * 8;
    for (int i = tid; i < 256; i += 256) hist[i] = 0;
    __syncthreads();
    u32 pfx = sh_prefix;
    int R = sh_R;
    for (int t = tid; t < n; t += 256) {
      u32 u = __builtin_bit_cast(u32, sr[t]);
      u = (u & 0x80000000u) ? ~u : (u | 0x80000000u);
      bool ok = (pass == 0) || ((u >> (shift + 8)) == (pfx >> (shift + 8)));
      if (ok) atomicAdd(&hist[(u >> shift) & 255], 1u);
    }
    __syncthreads();
    if (tid == 0) {
      int cum = 0, v = 255;
      for (; v >= 0; --v) {
        int c = (int)hist[v];
        if (cum + c >= R) break;
        cum += c;
      }
      sh_prefix = pfx | ((u32)v << shift);
      sh_R = R - cum;
    }
    __syncthreads();
  }
  const u32 thr = sh_prefix;
  const int R = sh_R;
  if (tid == 0) { sh_cnt = 0; sh_tiebase = 0; }
  __syncthreads();
  for (int t = tid; t < n; t += 256) {
    u32 u = __builtin_bit_cast(u32, sr[t]);
    u = (u & 0x80000000u) ? ~u : (u | 0x80000000u);
    if (u > thr) out[atomicAdd(&sh_cnt, 1)] = t;
  }
  __syncthreads();
  const int base = sh_cnt;  // == 512 - R
  for (int c0 = 0; c0 < n; c0 += 256) {
    int t = c0 + tid;
    bool f = false;
    if (t < n) {
      u32 u = __builtin_bit_cast(u32, sr[t]);
      u = (u & 0x80000000u) ? ~u : (u | 0x80000000u);
      f = (u == thr);
    }
    unsigned long long mk = __ballot(f);
    int lane = tid & 63, w = tid >> 6;
    int rank = __popcll(mk & ((1ull << lane) - 1ull));
    if (lane == 0) sh_wcnt[w] = __popcll(mk);
    __syncthreads();
    int wbase = 0;
    for (int i = 0; i < w; ++i) wbase += sh_wcnt[i];
    int tb = sh_tiebase;
    if (f) {
      int pos = tb + wbase + rank;
      if (pos < R) out[base + pos] = t;
    }
    __syncthreads();
    if (tid == 0) sh_tiebase = tb + sh_wcnt[0] + sh_wcnt[1] + sh_wcnt[2] + sh_wcnt[3];
    __syncthreads();
  }
}

// ---------- sparse attention over selected keys (v4) ----------
// Subtiled-transposed LDS layout for the 32-key x 576-col tile:
//   u16 addr(k, c) = (c>>4)*512 + ((k>>2)&1)*256 + (k>>3)*64 + (k&3)*16 + (c&15)
// Properties:
//  - 16B chunk index = (c>>4)*64 + lane where lane = r*32+g*8+j*2+ch  -> glds16 direct (linear dest)
//  - QK B-frag (8 consecutive c of one key) is one aligned b128 read
//  - PV  B-frag = 2x ds_read_b64_tr_b16 at addr = base + lane*8 bytes
//    (HW: lane l elem j <- base_u16 + (l>>4)*64 + j*16 + (l&15) = V[8g+4r+j][c0+l16])
__global__ __launch_bounds__(256) void k_attn(
    const int* __restrict__ sel, const u16* __restrict__ qabs, const u16* __restrict__ qpe,
    const u16* __restrict__ kvc, const u16* __restrict__ kpe, u16* __restrict__ oc) {
  const int bs = blockIdx.x;
  const int b = bs >> 11;
  const int tid = threadIdx.x;
  const int lane = tid & 63, wid = tid >> 6;
  const int g = lane >> 4, l16 = lane & 15;
  __shared__ __align__(16) u16 V_lds[36 * 512];   // 36 KB
  __shared__ float S_lds[2 * 16 * 36];
  __shared__ __align__(16) u16 P_lds[16 * 40];
  __shared__ int t_tile[32];
  __shared__ float m_lds[16], l_lds[16], f_lds[16];
  if (tid < 16) { m_lds[tid] = -3e38f; l_lds[tid] = 0.f; }
  const int half = wid >> 1, jhalf = wid & 1;
  const int kcb = half * 9;
  // Q fragments (A operand), registers
  bf16x8 qf[9];
  #pragma unroll
  for (int i = 0; i < 9; ++i) {
    int kc = kcb + i;
    if (kc < 16) qf[i] = *(const bf16x8*)(qabs + ((long)bs * 16 + l16) * 512 + kc * 32 + g * 8);
    else qf[i] = *(const bf16x8*)(qpe + ((long)bs * 16 + l16) * 64 + (kc - 16) * 32 + g * 8);
  }
  // gather lane constants: lane = r*32 + g'*8 + j*2 + ch  ->  k = 8g' + 4r + j
  const int gk = ((lane >> 3) & 3) * 8 + (lane >> 5) * 4 + ((lane >> 1) & 3);
  const int ch = lane & 1;
  // QK b128 read base (per-lane const part): key = jhalf*16 + l16
  const int key = jhalf * 16 + l16;
  const int keyoff = ((key >> 2) & 1) * 256 + (key >> 3) * 64 + (key & 3) * 16;
  f32x4 oacc[8];
  #pragma unroll
  for (int cf = 0; cf < 8; ++cf) oacc[cf] = (f32x4){0.f, 0.f, 0.f, 0.f};

  // ---- prologue: gather tile 0 ----
  {
    int t = sel[(long)bs * 512 + gk];
    int te = t < 0 ? 0 : t;
    if (wid == 0 && ch == 0) t_tile[gk] = t;
    const u16* srcv = kvc + ((long)(b * 2048 + te)) * 512 + ch * 8;
    const u16* srcp = kpe + ((long)(b * 2048 + te)) * 64 + ch * 8;
    #pragma unroll
    for (int q = 0; q < 9; ++q) {
      int cblk = wid * 9 + q;
      const u16* src = (cblk < 32) ? (srcv + cblk * 16) : (srcp + (cblk - 32) * 16);
      glds16(src, (char*)V_lds + cblk * 1024);
    }
  }
  __syncthreads();

  for (int jt = 0; jt < 16; ++jt) {
    // ---- QK^T from subtiled LDS ----
    f32x4 sacc = (f32x4){0.f, 0.f, 0.f, 0.f};
    #pragma unroll
    for (int i = 0; i < 9; ++i) {
      int kc = kcb + i;
      int addr = (kc * 2 + (g >> 1)) * 512 + keyoff + (g & 1) * 8;
      bf16x8 bfr = *(const bf16x8*)(V_lds + addr);
      sacc = __builtin_amdgcn_mfma_f32_16x16x32_bf16(qf[i], bfr, sacc, 0, 0, 0);
    }
    // ---- V fragments to registers via tr reads (V_lds free after this) ----
    s16x4 tv0[8], tv1[8];
    {
      u32 trb = lds_u32(V_lds) + (u32)(wid * 8192 + lane * 8);
      #pragma unroll
      for (int cf = 0; cf < 8; ++cf) {
        tv0[cf] = ds_tr16(trb + cf * 1024);
        tv1[cf] = ds_tr16(trb + cf * 1024 + 512);
      }
    }
    int tj = t_tile[key];
    #pragma unroll
    for (int r = 0; r < 4; ++r) {
      int h = g * 4 + r;
      S_lds[half * 576 + h * 36 + key] = (tj < 0) ? -1e30f : sacc[r] * 0.07216878364870322f;
    }
    __syncthreads();
    // ---- online softmax update ----
    {
      int h = tid >> 4, q16 = tid & 15;
      float vs[2];
      float mx = -3e38f;
      #pragma unroll
      for (int k = 0; k < 2; ++k) {
        int j = q16 + k * 16;
        vs[k] = S_lds[h * 36 + j] + S_lds[576 + h * 36 + j];
        mx = fmaxf(mx, vs[k]);
      }
      #pragma unroll
      for (int m = 1; m < 16; m <<= 1) mx = fmaxf(mx, __shfl_xor(mx, m, 64));
      float m_old = m_lds[h];
      float m_new = fmaxf(m_old, mx);
      float ps = 0.f;
      #pragma unroll
      for (int k = 0; k < 2; ++k) {
        float p = __expf(vs[k] - m_new);
        ps += p;
        P_lds[h * 40 + q16 + k * 16] = f2bf(p);
      }
      #pragma unroll
      for (int m = 1; m < 16; m <<= 1) ps += __shfl_xor(ps, m, 64);
      if (q16 == 0) {
        float f = __expf(m_old - m_new);
        f_lds[h] = f;
        m_lds[h] = m_new;
        l_lds[h] = l_lds[h] * f + ps;
      }
    }
    __syncthreads();
    // ---- issue next tile's gather (DMA writes V_lds; no wave reads it now) ----
    if (jt < 15) {
      int t = sel[(long)bs * 512 + (jt + 1) * 32 + gk];
      int te = t < 0 ? 0 : t;
      if (wid == 0 && ch == 0) t_tile[gk] = t;
      const u16* srcv = kvc + ((long)(b * 2048 + te)) * 512 + ch * 8;
      const u16* srcp = kpe + ((long)(b * 2048 + te)) * 64 + ch * 8;
      #pragma unroll
      for (int q = 0; q < 9; ++q) {
        int cblk = wid * 9 + q;
        const u16* src = (cblk < 32) ? (srcv + cblk * 16) : (srcp + (cblk - 32) * 16);
        glds16(src, (char*)V_lds + cblk * 1024);
      }
    }
    // ---- rescale + PV (V from registers) ----
    float fr[4];
    #pragma unroll
    for (int r = 0; r < 4; ++r) fr[r] = f_lds[g * 4 + r];
    bf16x8 pa = *(const bf16x8*)&P_lds[l16 * 40 + g * 8];
    #pragma unroll
    for (int cf = 0; cf < 8; ++cf) {
      #pragma unroll
      for (int r = 0; r < 4; ++r) oacc[cf][r] *= fr[r];
      bf16x8 vb = combine8(tv0[cf], tv1[cf]);
      oacc[cf] = __builtin_amdgcn_mfma_f32_16x16x32_bf16(pa, vb, oacc[cf], 0, 0, 0);
    }
    __syncthreads();
  }
  float li[4];
  #pragma unroll
  for (int r = 0; r < 4; ++r) li[r] = 1.0f / l_lds[g * 4 + r];
  #pragma unroll
  for (int cf = 0; cf < 8; ++cf) {
    int col = wid * 128 + cf * 16 + l16;
    #pragma unroll
    for (int r = 0; r < 4; ++r) {
      int h = g * 4 + r;
      oc[((long)bs * 16 + h) * 512 + col] = f2bf(oacc[cf][r] * li[r]);
    }
  }
}

// ---------- launcher ----------
extern "C" void kernel_launch(void* const* d_in, const int* in_sizes, int n_in,
                              void* d_out, int out_size, void* d_ws, size_t ws_size,
                              hipStream_t stream) {
  const float* x = (const float*)d_in[0];
  const float* fcos = (const float*)d_in[1];
  const float* fsin = (const float*)d_in[2];
  const float* wq_a = (const float*)d_in[4];
  const float* q_norm_w = (const float*)d_in[5];
  const float* wq_b = (const float*)d_in[6];
  const float* wkv_a = (const float*)d_in[7];
  const float* kv_norm_w = (const float*)d_in[8];
  const float* wkv_b = (const float*)d_in[9];
  const float* wo = (const float*)d_in[10];
  const float* idx_wq_b = (const float*)d_in[11];
  const float* idx_wk = (const float*)d_in[12];
  const float* iknw = (const float*)d_in[13];
  const float* iknb = (const float*)d_in[14];
  const float* iwp = (const float*)d_in[15];

  size_t off = 0;
  char* wsb = (char*)d_ws;
  auto alloc = [&](size_t bytes) -> char* {
    char* p = wsb + off;
    off += (bytes + 255) & ~(size_t)255;
    return p;
  };
  u16* x_b16  = (u16*)alloc(16777216);
  f16* xh     = (f16*)alloc(16777216);
  f16* xl     = (f16*)alloc(16777216);
  f16* wqa_h  = (f16*)alloc(3145728);
  f16* wqa_l  = (f16*)alloc(3145728);
  float* qr   = (float*)alloc(12582912);
  f16* qr_h   = (f16*)alloc(6291456);
  f16* qr_l   = (f16*)alloc(6291456);
  u16* qr_b   = (u16*)alloc(6291456);
  u16* wqb_b  = (u16*)alloc(4718592);
  char* QBIG  = alloc(50331648);          // q f32 -> idxq f32 -> scores f32 -> o_c bf16
  u16* qn_b   = (u16*)alloc(16777216);
  u16* qpe_b  = (u16*)alloc(8388608);
  u16* wkva_b = (u16*)alloc(2359296);
  float* kvraw= (float*)alloc(9437184);
  u16* kvc_b  = (u16*)alloc(4194304);
  u16* kpe_b  = (u16*)alloc(524288);
  u16* wkvb_b = (u16*)alloc(4194304);
  u16* wkvbnt = (u16*)alloc(2097152);
  u16* wo_b   = (u16*)alloc(8388608);
  f16* iwqb_h = (f16*)alloc(3145728);
  f16* iwqb_l = (f16*)alloc(3145728);
  f16* idxq_h = (f16*)alloc(16777216);
  f16* idxq_l = (f16*)alloc(16777216);
  f16* iwk_h  = (f16*)alloc(524288);
  f16* iwk_l  = (f16*)alloc(524288);
  float* idxk_f = (float*)alloc(2097152);
  f16* idxk_h = (f16*)alloc(1048576);
  f16* idxk_l = (f16*)alloc(1048576);
  float* idxw = (float*)alloc(262144);
  int* sel    = (int*)alloc(8388608);
  // aliases (lifetime-disjoint)
  u16* q_abs  = (u16*)xh;                 // xh+xl region, used after last xh/xl read
  float* q_f32 = (float*)QBIG;
  float* idxq_f32 = (float*)QBIG;
  float* scores = (float*)QBIG;
  u16* o_c    = (u16*)QBIG;
  u16* o_d    = (u16*)idxq_h;

  // 1. conversions / splits
  k_cvt_split_x<<<8192, 256, 0, stream>>>(x, x_b16, xh, xl, 8388608L);
  k_split<<<1536, 256, 0, stream>>>(wq_a, wqa_h, wqa_l, 1572864L);
  k_cvt_bf16<<<2304, 256, 0, stream>>>(wq_b, wqb_b, 2359296L);
  k_cvt_bf16<<<1152, 256, 0, stream>>>(wkv_a, wkva_b, 1179648L);
  k_cvt_wkvb<<<8192, 256, 0, stream>>>(wkv_b, wkvb_b, wkvbnt);
  k_cvt_bf16<<<4096, 256, 0, stream>>>(wo, wo_b, 4194304L);
  k_split<<<1536, 256, 0, stream>>>(idx_wq_b, iwqb_h, iwqb_l, 1572864L);
  k_split<<<256, 256, 0, stream>>>(idx_wk, iwk_h, iwk_l, 262144L);

  // 2. qr = rmsnorm(x @ wq_a.T)  [f32-accurate]
  k_gemm_f16pair<<<dim3(6, 32, 1), 256, 0, stream>>>(xh, xl, wqa_h, wqa_l, qr, 768, 2048, 2048, 2048, 768);
  k_rms_qr<<<4096, 256, 0, stream>>>(qr, q_norm_w, qr_h, qr_l, qr_b);

  // 3. q = qr @ wq_b.T  (bf16 ok) ; rope/split
  k_gemm_bt<<<dim3(24, 32, 1), 256, 0, stream>>>(qr_b, wqb_b, QBIG, 3072, 768, 768, 768, 3072, 0, 0, 0, 0);
  k_qpost<<<4096, 256, 0, stream>>>(q_f32, fcos, fsin, qn_b, qpe_b);

  // 4. kv = x @ wkv_a.T ; rms + rope
  k_gemm_bt<<<dim3(5, 32, 1), 256, 0, stream>>>(x_b16, wkva_b, kvraw, 576, 2048, 2048, 2048, 576, 0, 0, 0, 0);
  k_kvpost<<<4096, 256, 0, stream>>>(kvraw, kv_norm_w, fcos, fsin, kvc_b, kpe_b);

  // 5. indexer q/k/w  [f32-accurate]
  k_gemm_f16pair<<<dim3(16, 32, 1), 256, 0, stream>>>(qr_h, qr_l, iwqb_h, iwqb_l, idxq_f32, 2048, 768, 768, 768, 2048);
  k_idxqpost<<<4096, 256, 0, stream>>>(idxq_f32, fcos, fsin, idxq_h, idxq_l);
  k_gemm_f16pair<<<dim3(1, 32, 1), 256, 0, stream>>>(xh, xl, iwk_h, iwk_l, idxk_f, 128, 2048, 2048, 2048, 128);
  k_idxkpost<<<4096, 128, 0, stream>>>(idxk_f, iknw, iknb, fcos, fsin, idxk_h, idxk_l);
  k_wproj<<<4096, 256, 0, stream>>>(x, iwp, idxw);

  // 6. q_abs per head (after last use of xh/xl; writes over them)
  k_gemm_bt<<<dim3(4, 32, 16), 256, 0, stream>>>(qn_b, wkvbnt, q_abs, 512, 128, 2048, 128, 8192, 128, 65536, 512, 1);

  // 7. indexer scores (causal tiles) + exact top-512
  k_iscore<<<dim3(16, 32, 2), 256, 0, stream>>>(idxq_h, idxq_l, idxk_h, idxk_l, idxw, scores);
  k_topk<<<4096, 256, 0, stream>>>(scores, sel);

  // 8. sparse attention -> o_c  (overwrites scores region)
  k_attn<<<4096, 256, 0, stream>>>(sel, q_abs, qpe_b, kvc_b, kpe_b, o_c);

  // 9. o_d = per-head o_c @ wkv_b3[:,128:,:]  then  out = o_d @ wo.T
  k_gemm_bt<<<dim3(1, 32, 16), 256, 0, stream>>>(o_c, wkvb_b + 65536, o_d, 128, 512, 8192, 512, 2048, 512, 131072, 128, 1);
  k_gemm_bt<<<dim3(16, 32, 1), 256, 0, stream>>>(o_d, wo_b, d_out, 2048, 2048, 2048, 2048, 2048, 0, 0, 0, 0);
}